// Round 19
// baseline (238.038 us; speedup 1.0000x reference)
//
#include <hip/hip_runtime.h>
#include <hip/hip_cooperative_groups.h>

namespace cg = cooperative_groups;

#define BN_EPS 1e-5f

constexpr int PN0 = 262144, PN1 = 65536, PN2 = 16384, PN3 = 4096;
constexpr int NTHR = 1024;  // 16 waves/block, 1 block/CU -> 16 waves/CU
constexpr size_t MB = 1u << 20;

// Pin exactly 4 waves/EU -> 128-VGPR budget (r16/r17 failed because the compiler
// picked 8 waves/EU -> 64 VGPR -> spills; launch_bounds' 2nd arg is only a MIN).
#define KATTR __attribute__((amdgpu_waves_per_eu(4, 4)))

typedef __attribute__((ext_vector_type(8))) short short8;
typedef __attribute__((ext_vector_type(4))) float f32x4;
typedef __attribute__((ext_vector_type(4))) unsigned int u32x4;

__device__ __forceinline__ unsigned f2bf(float f) {
    unsigned u = __builtin_bit_cast(unsigned, f);
    u += 0x7fff + ((u >> 16) & 1);
    return u >> 16;
}
__device__ __forceinline__ float bf2f(unsigned h) {
    return __builtin_bit_cast(float, h << 16);
}
__device__ __forceinline__ f32x4 ntload4(const float* p) {
    return __builtin_nontemporal_load(reinterpret_cast<const f32x4*>(p));
}
__device__ __forceinline__ void ntstore4(float* p, f32x4 v) {
    __builtin_nontemporal_store(v, reinterpret_cast<f32x4*>(p));
}
#define SCHED_FENCE() __builtin_amdgcn_sched_barrier(0)

struct MegaArgs {
    const float *f0, *f1, *f2, *f3;
    const float *bnw2, *bnb2, *W2;
    const float *bnw1, *bnb1, *W1;
    const float *bnw0, *bnb0, *W0;
    const int *idx0, *idx1, *idx2;
    unsigned short *f3bf, *dec2, *dec1, *dec0, *f2p, *f1p;
    int *cnt2, *cnt1;
    float *part2, *part1, *part0;
    float *out;
};

// ---- quarter-block (256-thread) tree reduce of s/q[8] into part[vb] ----
template<int G, int NL>
__device__ __forceinline__ void red_write(float* aux, const float s[8], const float q[8],
                                          int t, int lr, int cgi,
                                          float* part, int vb, int C) {
    #pragma unroll
    for (int j = 0; j < 8; ++j) aux[(lr * G + cgi) * 8 + j] = s[j];
    __syncthreads();
    if (t < G) {
        float ss[8] = {};
        for (int l = 0; l < NL; ++l)
            #pragma unroll
            for (int j = 0; j < 8; ++j) ss[j] += aux[(l * G + t) * 8 + j];
        #pragma unroll
        for (int j = 0; j < 8; ++j)
            part[((size_t)vb * C + t * 8 + j) * 2] = ss[j];
    }
    __syncthreads();
    #pragma unroll
    for (int j = 0; j < 8; ++j) aux[(lr * G + cgi) * 8 + j] = q[j];
    __syncthreads();
    if (t < G) {
        float qq[8] = {};
        for (int l = 0; l < NL; ++l)
            #pragma unroll
            for (int j = 0; j < 8; ++j) qq[j] += aux[(l * G + t) * 8 + j];
        #pragma unroll
        for (int j = 0; j < 8; ++j)
            part[((size_t)vb * C + t * 8 + j) * 2 + 1] = qq[j];
    }
    __syncthreads();
}

// ---- P1a: unweighted stats over gathered f3[idx0] rows (128 rows / vb) ----
__device__ void stats_gathered(const MegaArgs& a, int vb, int t, float* aux) {
    const int cgi = t & 63, lr = t >> 6;
    const int r0 = vb * 128;
    float s[8] = {}, q[8] = {};
    for (int ii = 0; ii < 4; ++ii) {
        int gi[8];
        #pragma unroll
        for (int j = 0; j < 8; ++j) gi[j] = a.idx0[r0 + lr + 4 * (ii * 8 + j)];
        float4 x0[8], x1[8];
        #pragma unroll
        for (int j = 0; j < 8; ++j) {
            const float* p = a.f3 + (size_t)gi[j] * 512 + cgi * 8;
            x0[j] = *reinterpret_cast<const float4*>(p);
            x1[j] = *reinterpret_cast<const float4*>(p + 4);
        }
        SCHED_FENCE();
        #pragma unroll
        for (int j = 0; j < 8; ++j) {
            float v[8] = {x0[j].x, x0[j].y, x0[j].z, x0[j].w,
                          x1[j].x, x1[j].y, x1[j].z, x1[j].w};
            #pragma unroll
            for (int k = 0; k < 8; ++k) { s[k] += v[k]; q[k] += v[k] * v[k]; }
        }
    }
    red_write<64, 4>(aux, s, q, t, lr, cgi, a.part2, vb, 512);
}

// ---- P1b: f3 -> bf16 (32 rows / vb) ----
__device__ void cvt_f3(const MegaArgs& a, int vb, int t) {
    const int cgi = t & 63, lr = t >> 6;
    const int r0 = vb * 32;
    float4 x0[8], x1[8];
    #pragma unroll
    for (int i = 0; i < 8; ++i) {
        const float* p = a.f3 + (size_t)(r0 + lr + 4 * i) * 512 + cgi * 8;
        x0[i] = *reinterpret_cast<const float4*>(p);
        x1[i] = *reinterpret_cast<const float4*>(p + 4);
    }
    SCHED_FENCE();
    #pragma unroll
    for (int i = 0; i < 8; ++i) {
        uint4 o;
        o.x = f2bf(x0[i].x) | (f2bf(x0[i].y) << 16);
        o.y = f2bf(x0[i].z) | (f2bf(x0[i].w) << 16);
        o.z = f2bf(x1[i].x) | (f2bf(x1[i].y) << 16);
        o.w = f2bf(x1[i].z) | (f2bf(x1[i].w) << 16);
        *reinterpret_cast<uint4*>(a.f3bf + (size_t)(r0 + lr + 4 * i) * 512 + cgi * 8) = o;
    }
}

// ---- P1: stats-gathered || f3->bf16 || hist idx1 || hist idx2 (quarter-block) ----
// boundaries 128/256/288/416 divisible by 4 -> all quarters of a block same branch.
__device__ void phase1(const MegaArgs& a, int nbv, int vb0, int t, float* aux) {
    for (int vb = vb0; vb < 416; vb += nbv) {
        if (vb < 128) {
            stats_gathered(a, vb, t, aux);
        } else if (vb < 256) {
            cvt_f3(a, vb - 128, t);
        } else if (vb < 288) {
            int b = vb - 256;
            int v[8];
            #pragma unroll
            for (int i = 0; i < 8; ++i) v[i] = a.idx1[b * 2048 + i * 256 + t];
            SCHED_FENCE();
            #pragma unroll
            for (int i = 0; i < 8; ++i) atomicAdd(&a.cnt2[v[i]], 1);
        } else {
            int b = vb - 288;
            int v[8];
            #pragma unroll
            for (int i = 0; i < 8; ++i) v[i] = a.idx2[b * 2048 + i * 256 + t];
            SCHED_FENCE();
            #pragma unroll
            for (int i = 0; i < 8; ++i) atomicAdd(&a.cnt1[v[i]], 1);
        }
    }
}

// ---- per-block scale/shift from partials (into LDS), 1024 threads ----
template<int K, int NB>
__device__ void calc_scsh(int tid, const float* part, const float* bnw, const float* bnb,
                          float invN, float* sc, float* sh) {
    for (int c = tid; c < K; c += NTHR) {
        float s = 0.f, q = 0.f;
        for (int b = 0; b < NB; ++b) {
            float2 p = *reinterpret_cast<const float2*>(part + ((size_t)b * K + c) * 2);
            s += p.x;
            q += p.y;
        }
        float mean = s * invN;
        float var = fmaxf(q * invN - mean * mean, 0.f);
        float scl = bnw[c] * rsqrtf(var + BN_EPS);
        sc[c] = scl;
        sh[c] = bnb[c] - mean * scl;
    }
    __syncthreads();
}

// ---- G2: K=512, 256-row x 32-col tiles, whole 1024-thread block ----
__device__ void g2_phase(const MegaArgs& a, int nb, int bid, int tid,
                         unsigned short* Wl, float* sc, float* sh, float* dl) {
    constexpr int K = 512;
    calc_scsh<512, 128>(tid, a.part2, a.bnw2, a.bnb2, 1.f / PN2, sc, sh);
    const int lane = tid & 63;
    const int w = tid >> 6;                   // 16 waves
    const int l15 = lane & 15, lg = lane >> 4;
    const int n32 = tid >> 5, kc = tid & 31;  // 32 cols x 32 k-slices (16 k each)

    for (int vb = bid; vb < 128; vb += nb) {  // 16 chunks(256) x 8 panels(32)
        const int chunk = vb & 15, panel = vb >> 4;
        const int row = chunk * 256 + w * 16 + l15;
        const unsigned short* xp = a.f3bf + (size_t)row * K + lg * 8;
        short8 xf[16];
        #pragma unroll
        for (int kk = 0; kk < 16; ++kk)
            xf[kk] = *reinterpret_cast<const short8*>(xp + kk * 32);

        {
            const float* wrow = a.W2 + (size_t)(panel * 32 + n32) * K;
            float dp = 0.f;
            #pragma unroll
            for (int i = 0; i < 2; ++i) {
                int k = kc * 16 + i * 8;
                float4 w0 = *reinterpret_cast<const float4*>(wrow + k);
                float4 w1 = *reinterpret_cast<const float4*>(wrow + k + 4);
                float4 s0 = *reinterpret_cast<const float4*>(&sc[k]);
                float4 s1 = *reinterpret_cast<const float4*>(&sc[k + 4]);
                float4 h0 = *reinterpret_cast<const float4*>(&sh[k]);
                float4 h1 = *reinterpret_cast<const float4*>(&sh[k + 4]);
                dp += h0.x * w0.x + h0.y * w0.y + h0.z * w0.z + h0.w * w0.w
                    + h1.x * w1.x + h1.y * w1.y + h1.z * w1.z + h1.w * w1.w;
                uint4 o;
                o.x = f2bf(w0.x * s0.x) | (f2bf(w0.y * s0.y) << 16);
                o.y = f2bf(w0.z * s0.z) | (f2bf(w0.w * s0.w) << 16);
                o.z = f2bf(w1.x * s1.x) | (f2bf(w1.y * s1.y) << 16);
                o.w = f2bf(w1.z * s1.z) | (f2bf(w1.w * s1.w) << 16);
                int si = (n32 * K + k) ^ ((n32 & 7) << 3);
                *reinterpret_cast<uint4*>(&Wl[si]) = o;
            }
            dp += __shfl_xor(dp, 1); dp += __shfl_xor(dp, 2);
            dp += __shfl_xor(dp, 4); dp += __shfl_xor(dp, 8); dp += __shfl_xor(dp, 16);
            if (kc == 0) dl[n32] = dp;
        }
        __syncthreads();

        f32x4 acc[2];
        acc[0] = (f32x4){0.f, 0.f, 0.f, 0.f};
        acc[1] = (f32x4){0.f, 0.f, 0.f, 0.f};
        #pragma unroll
        for (int kk = 0; kk < 16; ++kk) {
            #pragma unroll
            for (int ni = 0; ni < 2; ++ni) {
                const int si = ((ni * 16 + l15) * K + kk * 32 + lg * 8) ^ ((l15 & 7) << 3);
                short8 wf = *reinterpret_cast<const short8*>(&Wl[si]);
                acc[ni] = __builtin_amdgcn_mfma_f32_16x16x32_bf16(wf, xf[kk], acc[ni], 0, 0, 0);
            }
        }

        const size_t rowoff = (size_t)row * 256 + panel * 32;
        #pragma unroll
        for (int ni = 0; ni < 2; ++ni) {
            float4 dr = *reinterpret_cast<const float4*>(&dl[ni * 16 + lg * 4]);
            size_t off = rowoff + ni * 16 + lg * 4;
            float v0 = dr.x + acc[ni][0];
            float v1 = dr.y + acc[ni][1];
            float v2 = dr.z + acc[ni][2];
            float v3 = dr.w + acc[ni][3];
            *reinterpret_cast<uint2*>(&a.dec2[off]) =
                make_uint2(f2bf(v0) | (f2bf(v1) << 16), f2bf(v2) | (f2bf(v3) << 16));
        }
        __syncthreads();
    }
}

// ---- G1: K=256, 256-row x 64-col tiles, whole 1024-thread block ----
__device__ void g1_phase(const MegaArgs& a, int nb, int bid, int tid,
                         unsigned short* Wl, float* sc, float* sh, float* dl) {
    constexpr int K = 256;
    calc_scsh<256, 256>(tid, a.part1, a.bnw1, a.bnb1, 1.f / PN1, sc, sh);
    const int lane = tid & 63;
    const int w = tid >> 6;
    const int l15 = lane & 15, lg = lane >> 4;
    const int n = tid >> 4, kc = tid & 15;  // 64 cols x 16 k-slices (16 k each)

    for (int vb = bid; vb < 128; vb += nb) {  // 64 chunks(256) x 2 panels(64)
        const int chunk = vb & 63, panel = vb >> 6;
        const int row = chunk * 256 + w * 16 + l15;
        const unsigned short* xp = a.f2p + (size_t)row * K + lg * 8;
        short8 xf[8];
        #pragma unroll
        for (int kk = 0; kk < 8; ++kk)
            xf[kk] = *reinterpret_cast<const short8*>(xp + kk * 32);

        {
            const float* wrow = a.W1 + (size_t)(panel * 64 + n) * K;
            float dp = 0.f;
            #pragma unroll
            for (int i = 0; i < 2; ++i) {
                int k = kc * 16 + i * 8;
                float4 w0 = *reinterpret_cast<const float4*>(wrow + k);
                float4 w1 = *reinterpret_cast<const float4*>(wrow + k + 4);
                float4 s0 = *reinterpret_cast<const float4*>(&sc[k]);
                float4 s1 = *reinterpret_cast<const float4*>(&sc[k + 4]);
                float4 h0 = *reinterpret_cast<const float4*>(&sh[k]);
                float4 h1 = *reinterpret_cast<const float4*>(&sh[k + 4]);
                dp += h0.x * w0.x + h0.y * w0.y + h0.z * w0.z + h0.w * w0.w
                    + h1.x * w1.x + h1.y * w1.y + h1.z * w1.z + h1.w * w1.w;
                uint4 o;
                o.x = f2bf(w0.x * s0.x) | (f2bf(w0.y * s0.y) << 16);
                o.y = f2bf(w0.z * s0.z) | (f2bf(w0.w * s0.w) << 16);
                o.z = f2bf(w1.x * s1.x) | (f2bf(w1.y * s1.y) << 16);
                o.w = f2bf(w1.z * s1.z) | (f2bf(w1.w * s1.w) << 16);
                int si = (n * K + k) ^ ((n & 7) << 3);
                *reinterpret_cast<uint4*>(&Wl[si]) = o;
            }
            dp += __shfl_xor(dp, 1); dp += __shfl_xor(dp, 2);
            dp += __shfl_xor(dp, 4); dp += __shfl_xor(dp, 8);
            if (kc == 0) dl[n] = dp;
        }
        __syncthreads();

        f32x4 acc[4];
        #pragma unroll
        for (int ni = 0; ni < 4; ++ni) acc[ni] = (f32x4){0.f, 0.f, 0.f, 0.f};
        #pragma unroll
        for (int kk = 0; kk < 8; ++kk) {
            #pragma unroll
            for (int ni = 0; ni < 4; ++ni) {
                const int si = ((ni * 16 + l15) * K + kk * 32 + lg * 8) ^ ((l15 & 7) << 3);
                short8 wf = *reinterpret_cast<const short8*>(&Wl[si]);
                acc[ni] = __builtin_amdgcn_mfma_f32_16x16x32_bf16(wf, xf[kk], acc[ni], 0, 0, 0);
            }
        }

        const size_t rowoff = (size_t)row * 128 + panel * 64;
        #pragma unroll
        for (int ni = 0; ni < 4; ++ni) {
            float4 dr = *reinterpret_cast<const float4*>(&dl[ni * 16 + lg * 4]);
            size_t off = rowoff + ni * 16 + lg * 4;
            float v0 = dr.x + acc[ni][0];
            float v1 = dr.y + acc[ni][1];
            float v2 = dr.z + acc[ni][2];
            float v3 = dr.w + acc[ni][3];
            *reinterpret_cast<uint2*>(&a.dec1[off]) =
                make_uint2(f2bf(v0) | (f2bf(v1) << 16), f2bf(v2) | (f2bf(v3) << 16));
        }
        __syncthreads();
    }
}

// ---- G0: K=128, 64-col panel staged once; 256-row tiles, grid-stride ----
// FIX: loop bound 256 (= PN1/256); r16/r17 had 1024 -> 4x OOB work + race.
__device__ void g0_phase(const MegaArgs& a, int nb, int bid, int tid,
                         unsigned short* Wl, float* sc, float* sh, float* dl) {
    constexpr int K = 128;
    calc_scsh<128, 512>(tid, a.part0, a.bnw0, a.bnb0, 1.f / PN0, sc, sh);
    const int lane = tid & 63;
    const int w = tid >> 6;
    const int l15 = lane & 15, lg = lane >> 4;
    const int n = tid >> 4, kc = tid & 15;  // 64 cols x 16 k-slices (8 k each)

    {
        const float* wrow = a.W0 + (size_t)n * K;
        int k = kc * 8;
        float4 w0 = *reinterpret_cast<const float4*>(wrow + k);
        float4 w1 = *reinterpret_cast<const float4*>(wrow + k + 4);
        float4 s0 = *reinterpret_cast<const float4*>(&sc[k]);
        float4 s1 = *reinterpret_cast<const float4*>(&sc[k + 4]);
        float4 h0 = *reinterpret_cast<const float4*>(&sh[k]);
        float4 h1 = *reinterpret_cast<const float4*>(&sh[k + 4]);
        float dp = h0.x * w0.x + h0.y * w0.y + h0.z * w0.z + h0.w * w0.w
                 + h1.x * w1.x + h1.y * w1.y + h1.z * w1.z + h1.w * w1.w;
        uint4 o;
        o.x = f2bf(w0.x * s0.x) | (f2bf(w0.y * s0.y) << 16);
        o.y = f2bf(w0.z * s0.z) | (f2bf(w0.w * s0.w) << 16);
        o.z = f2bf(w1.x * s1.x) | (f2bf(w1.y * s1.y) << 16);
        o.w = f2bf(w1.z * s1.z) | (f2bf(w1.w * s1.w) << 16);
        int si = (n * K + k) ^ ((n & 7) << 3);
        *reinterpret_cast<uint4*>(&Wl[si]) = o;
        dp += __shfl_xor(dp, 1); dp += __shfl_xor(dp, 2);
        dp += __shfl_xor(dp, 4); dp += __shfl_xor(dp, 8);
        if (kc == 0) dl[n] = dp;
    }
    __syncthreads();

    float4 dr[4];
    #pragma unroll
    for (int ni = 0; ni < 4; ++ni)
        dr[ni] = *reinterpret_cast<const float4*>(&dl[ni * 16 + lg * 4]);

    for (int vb = bid; vb < 256; vb += nb) {  // PN1/256 = 256 tiles
        const int row = vb * 256 + w * 16 + l15;
        const unsigned short* xp = a.f1p + (size_t)row * K + lg * 8;
        short8 xf[4];
        #pragma unroll
        for (int kk = 0; kk < 4; ++kk)
            xf[kk] = *reinterpret_cast<const short8*>(xp + kk * 32);
        f32x4 acc[4];
        #pragma unroll
        for (int ni = 0; ni < 4; ++ni) acc[ni] = (f32x4){0.f, 0.f, 0.f, 0.f};
        #pragma unroll
        for (int kk = 0; kk < 4; ++kk) {
            #pragma unroll
            for (int ni = 0; ni < 4; ++ni) {
                const int si = ((ni * 16 + l15) * K + kk * 32 + lg * 8) ^ ((l15 & 7) << 3);
                short8 wf = *reinterpret_cast<const short8*>(&Wl[si]);
                acc[ni] = __builtin_amdgcn_mfma_f32_16x16x32_bf16(wf, xf[kk], acc[ni], 0, 0, 0);
            }
        }
        const size_t rowoff = (size_t)row * 64;
        #pragma unroll
        for (int ni = 0; ni < 4; ++ni) {
            size_t off = rowoff + ni * 16 + lg * 4;
            float v0 = dr[ni].x + acc[ni][0];
            float v1 = dr[ni].y + acc[ni][1];
            float v2 = dr[ni].z + acc[ni][2];
            float v3 = dr[ni].w + acc[ni][3];
            *reinterpret_cast<uint2*>(&a.dec0[off]) =
                make_uint2(f2bf(v0) | (f2bf(v1) << 16), f2bf(v2) | (f2bf(v3) << 16));
        }
    }
}

// ---- batched gather-add, quarter-block (256-thread) body ----
template<int C, int IT, bool STATS, bool OUT_F32>
__device__ void ga_phase(int vb, int t, const float* base,
                         const unsigned short* dec, const int* idx,
                         const int* cnt_next, void* outv, float* part,
                         float* aux) {
    constexpr int G = C / 8;
    constexpr int NL = 256 / G;
    const int cgi = t % G;
    const int lr = t / G;
    const int r0 = vb * (NL * IT);

    int g[IT];
    #pragma unroll
    for (int i = 0; i < IT; ++i) g[i] = idx[r0 + lr + NL * i];

    float wreg[IT];
    if constexpr (STATS) {
        #pragma unroll
        for (int i = 0; i < IT; ++i) wreg[i] = (float)cnt_next[r0 + lr + NL * i];
    }

    u32x4 dv[IT];
    #pragma unroll
    for (int i = 0; i < IT; ++i)
        dv[i] = *reinterpret_cast<const u32x4*>(dec + (size_t)g[i] * C + cgi * 8);

    f32x4 b0[IT], b1[IT];
    #pragma unroll
    for (int i = 0; i < IT; ++i) {
        const float* bp = base + (size_t)(r0 + lr + NL * i) * C + cgi * 8;
        b0[i] = ntload4(bp);
        b1[i] = ntload4(bp + 4);
    }

    SCHED_FENCE();

    float s[8] = {}, q[8] = {};
    #pragma unroll
    for (int i = 0; i < IT; ++i) {
        const int r = r0 + lr + NL * i;
        float v[8];
        v[0] = b0[i][0] + bf2f(dv[i][0] & 0xffffu);
        v[1] = b0[i][1] + bf2f(dv[i][0] >> 16);
        v[2] = b0[i][2] + bf2f(dv[i][1] & 0xffffu);
        v[3] = b0[i][3] + bf2f(dv[i][1] >> 16);
        v[4] = b1[i][0] + bf2f(dv[i][2] & 0xffffu);
        v[5] = b1[i][1] + bf2f(dv[i][2] >> 16);
        v[6] = b1[i][2] + bf2f(dv[i][3] & 0xffffu);
        v[7] = b1[i][3] + bf2f(dv[i][3] >> 16);
        if constexpr (OUT_F32) {
            float* op = (float*)outv + (size_t)r * C + cgi * 8;
            ntstore4(op, (f32x4){v[0], v[1], v[2], v[3]});
            ntstore4(op + 4, (f32x4){v[4], v[5], v[6], v[7]});
        } else {
            unsigned h[8];
            #pragma unroll
            for (int j = 0; j < 8; ++j) h[j] = f2bf(v[j]);
            u32x4 o = {h[0] | (h[1] << 16), h[2] | (h[3] << 16),
                       h[4] | (h[5] << 16), h[6] | (h[7] << 16)};
            *reinterpret_cast<u32x4*>((unsigned short*)outv + (size_t)r * C + cgi * 8) = o;
            if constexpr (STATS) {
                #pragma unroll
                for (int j = 0; j < 8; ++j) {
                    float rv = bf2f(h[j]);
                    s[j] += wreg[i] * rv;
                    q[j] += wreg[i] * rv * rv;
                }
            }
        }
    }

    if constexpr (STATS)
        red_write<G, NL>(aux, s, q, t, lr, cgi, part, vb, C);
}

#define FENCE_SYNC { __threadfence(); gg.sync(); __threadfence(); }

// ================= cooperative mega-kernel: 1024-thr blocks, 7 phases, 6 syncs =================
__global__ KATTR __launch_bounds__(NTHR) void mega(MegaArgs a) {
    __shared__ __align__(16) char smemA[32768];  // Wl (G phases) / 4x aux (quarter phases)
    __shared__ float scshB[1088];                // sc|sh (<=1024) + dl(64)
    cg::grid_group gg = cg::this_grid();
    const int nb = gridDim.x;
    const int bid = blockIdx.x;
    const int tid = threadIdx.x;
    const int h = tid >> 8, t = tid & 255;       // quarter-block decomposition
    unsigned short* Wl = (unsigned short*)smemA;
    float* auxh = (float*)smemA + h * 2048;
    float* dl = scshB + 1024;

    phase1(a, nb * 4, bid * 4 + h, t, auxh);
    FENCE_SYNC;

    g2_phase(a, nb, bid, tid, Wl, scshB, scshB + 512, dl);
    FENCE_SYNC;

    for (int vb = bid * 4 + h; vb < 256; vb += nb * 4)
        ga_phase<256, 8, true, false>(vb, t, a.f2, a.dec2, a.idx0, a.cnt2, a.f2p, a.part1, auxh);
    FENCE_SYNC;

    g1_phase(a, nb, bid, tid, Wl, scshB, scshB + 256, dl);
    FENCE_SYNC;

    for (int vb = bid * 4 + h; vb < 512; vb += nb * 4)
        ga_phase<128, 8, true, false>(vb, t, a.f1, a.dec1, a.idx1, a.cnt1, a.f1p, a.part0, auxh);
    FENCE_SYNC;

    g0_phase(a, nb, bid, tid, Wl, scshB, scshB + 128, dl);
    FENCE_SYNC;

    for (int vb = bid * 4 + h; vb < 1024; vb += nb * 4)
        ga_phase<64, 8, false, true>(vb, t, a.f0, a.dec0, a.idx2, nullptr, a.out, nullptr, auxh);
}

// ================= fallback kernels (same phase bodies, 1024 threads) =================
__global__ KATTR __launch_bounds__(NTHR) void k_p1(MegaArgs a) {
    __shared__ float aux[8192];
    int h = threadIdx.x >> 8, t = threadIdx.x & 255;
    phase1(a, gridDim.x * 4, blockIdx.x * 4 + h, t, aux + h * 2048);
}
__global__ KATTR __launch_bounds__(NTHR) void k_g2(MegaArgs a) {
    __shared__ __align__(16) char smemA[32768];
    __shared__ float scshB[1088];
    g2_phase(a, gridDim.x, blockIdx.x, threadIdx.x, (unsigned short*)smemA,
             scshB, scshB + 512, scshB + 1024);
}
__global__ KATTR __launch_bounds__(NTHR) void k_g1(MegaArgs a) {
    __shared__ __align__(16) char smemA[32768];
    __shared__ float scshB[1088];
    g1_phase(a, gridDim.x, blockIdx.x, threadIdx.x, (unsigned short*)smemA,
             scshB, scshB + 256, scshB + 1024);
}
__global__ KATTR __launch_bounds__(NTHR) void k_g0(MegaArgs a) {
    __shared__ __align__(16) char smemA[16384];
    __shared__ float scshB[1088];
    g0_phase(a, gridDim.x, blockIdx.x, threadIdx.x, (unsigned short*)smemA,
             scshB, scshB + 128, scshB + 1024);
}
__global__ KATTR __launch_bounds__(NTHR) void k_a2(MegaArgs a) {
    __shared__ float aux[8192];
    int h = threadIdx.x >> 8, t = threadIdx.x & 255;
    for (int vb = blockIdx.x * 4 + h; vb < 256; vb += gridDim.x * 4)
        ga_phase<256, 8, true, false>(vb, t, a.f2, a.dec2, a.idx0, a.cnt2,
                                      a.f2p, a.part1, aux + h * 2048);
}
__global__ KATTR __launch_bounds__(NTHR) void k_a1(MegaArgs a) {
    __shared__ float aux[8192];
    int h = threadIdx.x >> 8, t = threadIdx.x & 255;
    for (int vb = blockIdx.x * 4 + h; vb < 512; vb += gridDim.x * 4)
        ga_phase<128, 8, true, false>(vb, t, a.f1, a.dec1, a.idx1, a.cnt1,
                                      a.f1p, a.part0, aux + h * 2048);
}
__global__ KATTR __launch_bounds__(NTHR) void k_a0(MegaArgs a) {
    int h = threadIdx.x >> 8, t = threadIdx.x & 255;
    for (int vb = blockIdx.x * 4 + h; vb < 1024; vb += gridDim.x * 4)
        ga_phase<64, 8, false, true>(vb, t, a.f0, a.dec0, a.idx2, nullptr,
                                     a.out, nullptr, nullptr);
}

extern "C" void kernel_launch(void* const* d_in, const int* in_sizes, int n_in,
                              void* d_out, int out_size, void* d_ws, size_t ws_size,
                              hipStream_t stream) {
    // ---- workspace layout ----
    char* wsb = (char*)d_ws;
    unsigned short* f3bf = (unsigned short*)wsb;              // 4MB
    unsigned short* dec2 = (unsigned short*)(wsb + 4 * MB);   // 2MB
    unsigned short* dec1 = (unsigned short*)(wsb + 6 * MB);   // 4MB
    unsigned short* dec0 = (unsigned short*)(wsb + 10 * MB);  // 8MB
    unsigned short* f2p  = (unsigned short*)(wsb + 18 * MB);  // 8MB
    unsigned short* f1p  = (unsigned short*)(wsb + 26 * MB);  // 16MB
    int* cnt2 = (int*)(wsb + 42 * MB);                        // contiguous zero region
    int* cnt1 = cnt2 + PN2;
    float* part2 = (float*)(cnt1 + PN1);                      // 128*512*2
    float* part1 = part2 + 128 * 512 * 2;                     // 256*256*2
    float* part0 = part1 + 256 * 256 * 2;                     // 512*128*2

    MegaArgs a;
    a.f0 = (const float*)d_in[0];
    a.f1 = (const float*)d_in[1];
    a.f2 = (const float*)d_in[2];
    a.f3 = (const float*)d_in[3];
    a.bnw2 = (const float*)d_in[4];
    a.bnb2 = (const float*)d_in[5];
    a.W2 = (const float*)d_in[6];
    a.bnw1 = (const float*)d_in[7];
    a.bnb1 = (const float*)d_in[8];
    a.W1 = (const float*)d_in[9];
    a.bnw0 = (const float*)d_in[10];
    a.bnb0 = (const float*)d_in[11];
    a.W0 = (const float*)d_in[12];
    a.idx0 = (const int*)d_in[13];
    a.idx1 = (const int*)d_in[14];
    a.idx2 = (const int*)d_in[15];
    a.f3bf = f3bf; a.dec2 = dec2; a.dec1 = dec1; a.dec0 = dec0;
    a.f2p = f2p; a.f1p = f1p;
    a.cnt2 = cnt2; a.cnt1 = cnt1;
    a.part2 = part2; a.part1 = part1; a.part0 = part0;
    a.out = (float*)d_out;

    hipMemsetAsync(cnt2, 0, (size_t)(PN2 + PN1) * sizeof(int), stream);

    int dev = 0;
    hipGetDevice(&dev);
    int coop = 0;
    hipDeviceGetAttribute(&coop, hipDeviceAttributeCooperativeLaunch, dev);
    int maxb = 0;
    hipOccupancyMaxActiveBlocksPerMultiprocessor(&maxb, mega, NTHR, 0);

    if (coop && maxb >= 1) {
        void* kargs[] = {&a};
        hipLaunchCooperativeKernel((void*)mega, dim3(256), dim3(NTHR), kargs, 0, stream);
    } else {
        k_p1<<<104, NTHR, 0, stream>>>(a);
        k_g2<<<128, NTHR, 0, stream>>>(a);
        k_a2<<<64, NTHR, 0, stream>>>(a);
        k_g1<<<128, NTHR, 0, stream>>>(a);
        k_a1<<<128, NTHR, 0, stream>>>(a);
        k_g0<<<256, NTHR, 0, stream>>>(a);
        k_a0<<<256, NTHR, 0, stream>>>(a);
    }
}

// Round 20
// 163.874 us; speedup vs baseline: 1.4526x; 1.4526x over previous
//
#include <hip/hip_runtime.h>

#define BN_EPS 1e-5f

constexpr int PN0 = 262144, PN1 = 65536, PN2 = 16384, PN3 = 4096;
constexpr size_t MB = 1u << 20;

typedef __attribute__((ext_vector_type(8))) short short8;
typedef __attribute__((ext_vector_type(4))) float f32x4;
typedef __attribute__((ext_vector_type(4))) unsigned int u32x4;

__device__ __forceinline__ unsigned f2bf(float f) {
    unsigned u = __builtin_bit_cast(unsigned, f);
    u += 0x7fff + ((u >> 16) & 1);
    return u >> 16;
}
__device__ __forceinline__ float bf2f(unsigned h) {
    return __builtin_bit_cast(float, h << 16);
}
__device__ __forceinline__ f32x4 ntload4(const float* p) {
    return __builtin_nontemporal_load(reinterpret_cast<const f32x4*>(p));
}
__device__ __forceinline__ void ntstore4(float* p, f32x4 v) {
    __builtin_nontemporal_store(v, reinterpret_cast<f32x4*>(p));
}
#define SCHED_FENCE() __builtin_amdgcn_sched_barrier(0)

struct MegaArgs {
    const float *f0, *f1, *f2, *f3;
    const float *bnw2, *bnb2, *W2;
    const float *bnw1, *bnb1, *W1;
    const float *bnw0, *bnb0, *W0;
    const int *idx0, *idx1, *idx2;
    unsigned short *f3bf, *dec2, *dec1, *dec0, *f2p, *f1p;
    int *cnt2, *cnt1;
    float *part2, *part1, *part0;
    float *out;
};

// ---- 256-thread tree reduce of s/q[8] into part[vb] ----
template<int G, int NL>
__device__ __forceinline__ void red_write(float* aux, const float s[8], const float q[8],
                                          int t, int lr, int cgi,
                                          float* part, int vb, int C) {
    #pragma unroll
    for (int j = 0; j < 8; ++j) aux[(lr * G + cgi) * 8 + j] = s[j];
    __syncthreads();
    if (t < G) {
        float ss[8] = {};
        for (int l = 0; l < NL; ++l)
            #pragma unroll
            for (int j = 0; j < 8; ++j) ss[j] += aux[(l * G + t) * 8 + j];
        #pragma unroll
        for (int j = 0; j < 8; ++j)
            part[((size_t)vb * C + t * 8 + j) * 2] = ss[j];
    }
    __syncthreads();
    #pragma unroll
    for (int j = 0; j < 8; ++j) aux[(lr * G + cgi) * 8 + j] = q[j];
    __syncthreads();
    if (t < G) {
        float qq[8] = {};
        for (int l = 0; l < NL; ++l)
            #pragma unroll
            for (int j = 0; j < 8; ++j) qq[j] += aux[(l * G + t) * 8 + j];
        #pragma unroll
        for (int j = 0; j < 8; ++j)
            part[((size_t)vb * C + t * 8 + j) * 2 + 1] = qq[j];
    }
}

// ---- P1: stats over gathered f3[idx0] (vb<128) || f3->bf16 (vb<256) || hists ----
__global__ __launch_bounds__(256, 4) void k_p1(MegaArgs a) {
    __shared__ float aux[2048];
    const int vb = blockIdx.x;
    const int t = threadIdx.x;
    if (vb < 128) {
        const int cgi = t & 63, lr = t >> 6;
        const int r0 = vb * 128;
        float s[8] = {}, q[8] = {};
        for (int ii = 0; ii < 4; ++ii) {
            int gi[8];
            #pragma unroll
            for (int j = 0; j < 8; ++j) gi[j] = a.idx0[r0 + lr + 4 * (ii * 8 + j)];
            float4 x0[8], x1[8];
            #pragma unroll
            for (int j = 0; j < 8; ++j) {
                const float* p = a.f3 + (size_t)gi[j] * 512 + cgi * 8;
                x0[j] = *reinterpret_cast<const float4*>(p);
                x1[j] = *reinterpret_cast<const float4*>(p + 4);
            }
            SCHED_FENCE();
            #pragma unroll
            for (int j = 0; j < 8; ++j) {
                float v[8] = {x0[j].x, x0[j].y, x0[j].z, x0[j].w,
                              x1[j].x, x1[j].y, x1[j].z, x1[j].w};
                #pragma unroll
                for (int k = 0; k < 8; ++k) { s[k] += v[k]; q[k] += v[k] * v[k]; }
            }
        }
        red_write<64, 4>(aux, s, q, t, lr, cgi, a.part2, vb, 512);
    } else if (vb < 256) {
        const int cgi = t & 63, lr = t >> 6;
        const int r0 = (vb - 128) * 32;
        float4 x0[8], x1[8];
        #pragma unroll
        for (int i = 0; i < 8; ++i) {
            const float* p = a.f3 + (size_t)(r0 + lr + 4 * i) * 512 + cgi * 8;
            x0[i] = *reinterpret_cast<const float4*>(p);
            x1[i] = *reinterpret_cast<const float4*>(p + 4);
        }
        SCHED_FENCE();
        #pragma unroll
        for (int i = 0; i < 8; ++i) {
            uint4 o;
            o.x = f2bf(x0[i].x) | (f2bf(x0[i].y) << 16);
            o.y = f2bf(x0[i].z) | (f2bf(x0[i].w) << 16);
            o.z = f2bf(x1[i].x) | (f2bf(x1[i].y) << 16);
            o.w = f2bf(x1[i].z) | (f2bf(x1[i].w) << 16);
            *reinterpret_cast<uint4*>(a.f3bf + (size_t)(r0 + lr + 4 * i) * 512 + cgi * 8) = o;
        }
    } else if (vb < 288) {
        int b = vb - 256;
        int v[8];
        #pragma unroll
        for (int i = 0; i < 8; ++i) v[i] = a.idx1[b * 2048 + i * 256 + t];
        SCHED_FENCE();
        #pragma unroll
        for (int i = 0; i < 8; ++i) atomicAdd(&a.cnt2[v[i]], 1);
    } else {
        int b = vb - 288;
        int v[8];
        #pragma unroll
        for (int i = 0; i < 8; ++i) v[i] = a.idx2[b * 2048 + i * 256 + t];
        SCHED_FENCE();
        #pragma unroll
        for (int i = 0; i < 8; ++i) atomicAdd(&a.cnt1[v[i]], 1);
    }
}

// ---- per-block scale/shift from partials (into LDS), NT threads ----
template<int K, int NB, int NT>
__device__ void calc_scsh(int tid, const float* part, const float* bnw, const float* bnb,
                          float invN, float* sc, float* sh) {
    for (int c = tid; c < K; c += NT) {
        float s = 0.f, q = 0.f;
        for (int b = 0; b < NB; ++b) {
            float2 p = *reinterpret_cast<const float2*>(part + ((size_t)b * K + c) * 2);
            s += p.x;
            q += p.y;
        }
        float mean = s * invN;
        float var = fmaxf(q * invN - mean * mean, 0.f);
        float scl = bnw[c] * rsqrtf(var + BN_EPS);
        sc[c] = scl;
        sh[c] = bnb[c] - mean * scl;
    }
    __syncthreads();
}

// ---- G2: K=512, 128-row x 32-col tile per block (512 thr), vb=blockIdx ----
__global__ __launch_bounds__(512, 4) void k_g2(MegaArgs a) {
    constexpr int K = 512;
    __shared__ __align__(16) unsigned short Wl[32 * 512];  // 32KB
    __shared__ float scshB[1088];
    float* sc = scshB;
    float* sh = scshB + 512;
    float* dl = scshB + 1024;
    const int tid = threadIdx.x;
    calc_scsh<512, 128, 512>(tid, a.part2, a.bnw2, a.bnb2, 1.f / PN2, sc, sh);
    const int lane = tid & 63;
    const int w = tid >> 6;
    const int l15 = lane & 15, lg = lane >> 4;
    const int n32 = tid >> 4, kc = tid & 15;

    const int vb = blockIdx.x;              // 256 = 32 chunks(128) x 8 panels(32)
    const int chunk = vb & 31, panel = vb >> 5;
    const int row = chunk * 128 + w * 16 + l15;
    const unsigned short* xp = a.f3bf + (size_t)row * K + lg * 8;
    short8 xf[16];
    #pragma unroll
    for (int kk = 0; kk < 16; ++kk)
        xf[kk] = *reinterpret_cast<const short8*>(xp + kk * 32);

    {
        const float* wrow = a.W2 + (size_t)(panel * 32 + n32) * K;
        float dp = 0.f;
        #pragma unroll
        for (int i = 0; i < 4; ++i) {
            int k = kc * 32 + i * 8;
            float4 w0 = *reinterpret_cast<const float4*>(wrow + k);
            float4 w1 = *reinterpret_cast<const float4*>(wrow + k + 4);
            float4 s0 = *reinterpret_cast<const float4*>(&sc[k]);
            float4 s1 = *reinterpret_cast<const float4*>(&sc[k + 4]);
            float4 h0 = *reinterpret_cast<const float4*>(&sh[k]);
            float4 h1 = *reinterpret_cast<const float4*>(&sh[k + 4]);
            dp += h0.x * w0.x + h0.y * w0.y + h0.z * w0.z + h0.w * w0.w
                + h1.x * w1.x + h1.y * w1.y + h1.z * w1.z + h1.w * w1.w;
            uint4 o;
            o.x = f2bf(w0.x * s0.x) | (f2bf(w0.y * s0.y) << 16);
            o.y = f2bf(w0.z * s0.z) | (f2bf(w0.w * s0.w) << 16);
            o.z = f2bf(w1.x * s1.x) | (f2bf(w1.y * s1.y) << 16);
            o.w = f2bf(w1.z * s1.z) | (f2bf(w1.w * s1.w) << 16);
            int si = (n32 * K + k) ^ ((n32 & 7) << 3);
            *reinterpret_cast<uint4*>(&Wl[si]) = o;
        }
        dp += __shfl_xor(dp, 1); dp += __shfl_xor(dp, 2);
        dp += __shfl_xor(dp, 4); dp += __shfl_xor(dp, 8);
        if (kc == 0) dl[n32] = dp;
    }
    __syncthreads();

    f32x4 acc[2];
    acc[0] = (f32x4){0.f, 0.f, 0.f, 0.f};
    acc[1] = (f32x4){0.f, 0.f, 0.f, 0.f};
    #pragma unroll
    for (int kk = 0; kk < 16; ++kk) {
        #pragma unroll
        for (int ni = 0; ni < 2; ++ni) {
            const int si = ((ni * 16 + l15) * K + kk * 32 + lg * 8) ^ ((l15 & 7) << 3);
            short8 wf = *reinterpret_cast<const short8*>(&Wl[si]);
            acc[ni] = __builtin_amdgcn_mfma_f32_16x16x32_bf16(wf, xf[kk], acc[ni], 0, 0, 0);
        }
    }

    const size_t rowoff = (size_t)row * 256 + panel * 32;
    #pragma unroll
    for (int ni = 0; ni < 2; ++ni) {
        float4 dr = *reinterpret_cast<const float4*>(&dl[ni * 16 + lg * 4]);
        size_t off = rowoff + ni * 16 + lg * 4;
        float v0 = dr.x + acc[ni][0];
        float v1 = dr.y + acc[ni][1];
        float v2 = dr.z + acc[ni][2];
        float v3 = dr.w + acc[ni][3];
        *reinterpret_cast<uint2*>(&a.dec2[off]) =
            make_uint2(f2bf(v0) | (f2bf(v1) << 16), f2bf(v2) | (f2bf(v3) << 16));
    }
}

// ---- G1: K=256, 128-row x 64-col tile per block (512 thr), vb=blockIdx ----
__global__ __launch_bounds__(512, 4) void k_g1(MegaArgs a) {
    constexpr int K = 256;
    __shared__ __align__(16) unsigned short Wl[64 * 256];  // 32KB
    __shared__ float scshB[576];
    float* sc = scshB;
    float* sh = scshB + 256;
    float* dl = scshB + 512;
    const int tid = threadIdx.x;
    calc_scsh<256, 256, 512>(tid, a.part1, a.bnw1, a.bnb1, 1.f / PN1, sc, sh);
    const int lane = tid & 63;
    const int w = tid >> 6;
    const int l15 = lane & 15, lg = lane >> 4;
    const int n = tid >> 3, kc = tid & 7;

    const int vb = blockIdx.x;              // 256 = 128 chunks(128) x 2 panels(64)
    const int chunk = vb & 127, panel = vb >> 7;
    const int row = chunk * 128 + w * 16 + l15;
    const unsigned short* xp = a.f2p + (size_t)row * K + lg * 8;
    short8 xf[8];
    #pragma unroll
    for (int kk = 0; kk < 8; ++kk)
        xf[kk] = *reinterpret_cast<const short8*>(xp + kk * 32);

    {
        const float* wrow = a.W1 + (size_t)(panel * 64 + n) * K;
        float dp = 0.f;
        #pragma unroll
        for (int i = 0; i < 4; ++i) {
            int k = kc * 32 + i * 8;
            float4 w0 = *reinterpret_cast<const float4*>(wrow + k);
            float4 w1 = *reinterpret_cast<const float4*>(wrow + k + 4);
            float4 s0 = *reinterpret_cast<const float4*>(&sc[k]);
            float4 s1 = *reinterpret_cast<const float4*>(&sc[k + 4]);
            float4 h0 = *reinterpret_cast<const float4*>(&sh[k]);
            float4 h1 = *reinterpret_cast<const float4*>(&sh[k + 4]);
            dp += h0.x * w0.x + h0.y * w0.y + h0.z * w0.z + h0.w * w0.w
                + h1.x * w1.x + h1.y * w1.y + h1.z * w1.z + h1.w * w1.w;
            uint4 o;
            o.x = f2bf(w0.x * s0.x) | (f2bf(w0.y * s0.y) << 16);
            o.y = f2bf(w0.z * s0.z) | (f2bf(w0.w * s0.w) << 16);
            o.z = f2bf(w1.x * s1.x) | (f2bf(w1.y * s1.y) << 16);
            o.w = f2bf(w1.z * s1.z) | (f2bf(w1.w * s1.w) << 16);
            int si = (n * K + k) ^ ((n & 7) << 3);
            *reinterpret_cast<uint4*>(&Wl[si]) = o;
        }
        dp += __shfl_xor(dp, 1); dp += __shfl_xor(dp, 2); dp += __shfl_xor(dp, 4);
        if (kc == 0) dl[n] = dp;
    }
    __syncthreads();

    f32x4 acc[4];
    #pragma unroll
    for (int ni = 0; ni < 4; ++ni) acc[ni] = (f32x4){0.f, 0.f, 0.f, 0.f};
    #pragma unroll
    for (int kk = 0; kk < 8; ++kk) {
        #pragma unroll
        for (int ni = 0; ni < 4; ++ni) {
            const int si = ((ni * 16 + l15) * K + kk * 32 + lg * 8) ^ ((l15 & 7) << 3);
            short8 wf = *reinterpret_cast<const short8*>(&Wl[si]);
            acc[ni] = __builtin_amdgcn_mfma_f32_16x16x32_bf16(wf, xf[kk], acc[ni], 0, 0, 0);
        }
    }

    const size_t rowoff = (size_t)row * 128 + panel * 64;
    #pragma unroll
    for (int ni = 0; ni < 4; ++ni) {
        float4 dr = *reinterpret_cast<const float4*>(&dl[ni * 16 + lg * 4]);
        size_t off = rowoff + ni * 16 + lg * 4;
        float v0 = dr.x + acc[ni][0];
        float v1 = dr.y + acc[ni][1];
        float v2 = dr.z + acc[ni][2];
        float v3 = dr.w + acc[ni][3];
        *reinterpret_cast<uint2*>(&a.dec1[off]) =
            make_uint2(f2bf(v0) | (f2bf(v1) << 16), f2bf(v2) | (f2bf(v3) << 16));
    }
}

// ---- G0: K=128, 64-col panel staged per block; 128-row tile, vb=blockIdx ----
__global__ __launch_bounds__(512, 4) void k_g0(MegaArgs a) {
    constexpr int K = 128;
    __shared__ __align__(16) unsigned short Wl[64 * 128];  // 16KB
    __shared__ float scshB[320];
    float* sc = scshB;
    float* sh = scshB + 128;
    float* dl = scshB + 256;
    const int tid = threadIdx.x;
    calc_scsh<128, 512, 512>(tid, a.part0, a.bnw0, a.bnb0, 1.f / PN0, sc, sh);
    const int lane = tid & 63;
    const int w = tid >> 6;
    const int l15 = lane & 15, lg = lane >> 4;
    const int n = tid >> 3, kc = tid & 7;

    {
        const float* wrow = a.W0 + (size_t)n * K;
        float dp = 0.f;
        #pragma unroll
        for (int i = 0; i < 2; ++i) {
            int k = kc * 16 + i * 8;
            float4 w0 = *reinterpret_cast<const float4*>(wrow + k);
            float4 w1 = *reinterpret_cast<const float4*>(wrow + k + 4);
            float4 s0 = *reinterpret_cast<const float4*>(&sc[k]);
            float4 s1 = *reinterpret_cast<const float4*>(&sc[k + 4]);
            float4 h0 = *reinterpret_cast<const float4*>(&sh[k]);
            float4 h1 = *reinterpret_cast<const float4*>(&sh[k + 4]);
            dp += h0.x * w0.x + h0.y * w0.y + h0.z * w0.z + h0.w * w0.w
                + h1.x * w1.x + h1.y * w1.y + h1.z * w1.z + h1.w * w1.w;
            uint4 o;
            o.x = f2bf(w0.x * s0.x) | (f2bf(w0.y * s0.y) << 16);
            o.y = f2bf(w0.z * s0.z) | (f2bf(w0.w * s0.w) << 16);
            o.z = f2bf(w1.x * s1.x) | (f2bf(w1.y * s1.y) << 16);
            o.w = f2bf(w1.z * s1.z) | (f2bf(w1.w * s1.w) << 16);
            int si = (n * K + k) ^ ((n & 7) << 3);
            *reinterpret_cast<uint4*>(&Wl[si]) = o;
        }
        dp += __shfl_xor(dp, 1); dp += __shfl_xor(dp, 2); dp += __shfl_xor(dp, 4);
        if (kc == 0) dl[n] = dp;
    }
    __syncthreads();

    float4 dr[4];
    #pragma unroll
    for (int ni = 0; ni < 4; ++ni)
        dr[ni] = *reinterpret_cast<const float4*>(&dl[ni * 16 + lg * 4]);

    const int vb = blockIdx.x;  // 512 tiles of 128 rows (PN1/128)
    const int row = vb * 128 + w * 16 + l15;
    const unsigned short* xp = a.f1p + (size_t)row * K + lg * 8;
    short8 xf[4];
    #pragma unroll
    for (int kk = 0; kk < 4; ++kk)
        xf[kk] = *reinterpret_cast<const short8*>(xp + kk * 32);
    f32x4 acc[4];
    #pragma unroll
    for (int ni = 0; ni < 4; ++ni) acc[ni] = (f32x4){0.f, 0.f, 0.f, 0.f};
    #pragma unroll
    for (int kk = 0; kk < 4; ++kk) {
        #pragma unroll
        for (int ni = 0; ni < 4; ++ni) {
            const int si = ((ni * 16 + l15) * K + kk * 32 + lg * 8) ^ ((l15 & 7) << 3);
            short8 wf = *reinterpret_cast<const short8*>(&Wl[si]);
            acc[ni] = __builtin_amdgcn_mfma_f32_16x16x32_bf16(wf, xf[kk], acc[ni], 0, 0, 0);
        }
    }
    const size_t rowoff = (size_t)row * 64;
    #pragma unroll
    for (int ni = 0; ni < 4; ++ni) {
        size_t off = rowoff + ni * 16 + lg * 4;
        float v0 = dr[ni].x + acc[ni][0];
        float v1 = dr[ni].y + acc[ni][1];
        float v2 = dr[ni].z + acc[ni][2];
        float v3 = dr[ni].w + acc[ni][3];
        *reinterpret_cast<uint2*>(&a.dec0[off]) =
            make_uint2(f2bf(v0) | (f2bf(v1) << 16), f2bf(v2) | (f2bf(v3) << 16));
    }
}

// ---- batched gather-add (256-thread block, vb=blockIdx) ----
template<int C, int IT, bool STATS, bool OUT_F32>
__device__ void ga_body(int vb, int t, const float* base,
                        const unsigned short* dec, const int* idx,
                        const int* cnt_next, void* outv, float* part,
                        float* aux) {
    constexpr int G = C / 8;
    constexpr int NL = 256 / G;
    const int cgi = t % G;
    const int lr = t / G;
    const int r0 = vb * (NL * IT);

    int g[IT];
    #pragma unroll
    for (int i = 0; i < IT; ++i) g[i] = idx[r0 + lr + NL * i];

    float wreg[IT];
    if constexpr (STATS) {
        #pragma unroll
        for (int i = 0; i < IT; ++i) wreg[i] = (float)cnt_next[r0 + lr + NL * i];
    }

    u32x4 dv[IT];
    #pragma unroll
    for (int i = 0; i < IT; ++i)
        dv[i] = *reinterpret_cast<const u32x4*>(dec + (size_t)g[i] * C + cgi * 8);

    f32x4 b0[IT], b1[IT];
    #pragma unroll
    for (int i = 0; i < IT; ++i) {
        const float* bp = base + (size_t)(r0 + lr + NL * i) * C + cgi * 8;
        b0[i] = ntload4(bp);
        b1[i] = ntload4(bp + 4);
    }

    SCHED_FENCE();

    float s[8] = {}, q[8] = {};
    #pragma unroll
    for (int i = 0; i < IT; ++i) {
        const int r = r0 + lr + NL * i;
        float v[8];
        v[0] = b0[i][0] + bf2f(dv[i][0] & 0xffffu);
        v[1] = b0[i][1] + bf2f(dv[i][0] >> 16);
        v[2] = b0[i][2] + bf2f(dv[i][1] & 0xffffu);
        v[3] = b0[i][3] + bf2f(dv[i][1] >> 16);
        v[4] = b1[i][0] + bf2f(dv[i][2] & 0xffffu);
        v[5] = b1[i][1] + bf2f(dv[i][2] >> 16);
        v[6] = b1[i][2] + bf2f(dv[i][3] & 0xffffu);
        v[7] = b1[i][3] + bf2f(dv[i][3] >> 16);
        if constexpr (OUT_F32) {
            float* op = (float*)outv + (size_t)r * C + cgi * 8;
            ntstore4(op, (f32x4){v[0], v[1], v[2], v[3]});
            ntstore4(op + 4, (f32x4){v[4], v[5], v[6], v[7]});
        } else {
            unsigned h[8];
            #pragma unroll
            for (int j = 0; j < 8; ++j) h[j] = f2bf(v[j]);
            u32x4 o = {h[0] | (h[1] << 16), h[2] | (h[3] << 16),
                       h[4] | (h[5] << 16), h[6] | (h[7] << 16)};
            *reinterpret_cast<u32x4*>((unsigned short*)outv + (size_t)r * C + cgi * 8) = o;
            if constexpr (STATS) {
                #pragma unroll
                for (int j = 0; j < 8; ++j) {
                    float rv = bf2f(h[j]);
                    s[j] += wreg[i] * rv;
                    q[j] += wreg[i] * rv * rv;
                }
            }
        }
    }

    if constexpr (STATS)
        red_write<G, NL>(aux, s, q, t, lr, cgi, part, vb, C);
}

__global__ __launch_bounds__(256, 4) void k_a2(MegaArgs a) {
    __shared__ float aux[2048];
    ga_body<256, 8, true, false>(blockIdx.x, threadIdx.x, a.f2, a.dec2, a.idx0, a.cnt2,
                                 a.f2p, a.part1, aux);
}
__global__ __launch_bounds__(256, 4) void k_a1(MegaArgs a) {
    __shared__ float aux[2048];
    ga_body<128, 8, true, false>(blockIdx.x, threadIdx.x, a.f1, a.dec1, a.idx1, a.cnt1,
                                 a.f1p, a.part0, aux);
}
__global__ __launch_bounds__(256, 4) void k_a0(MegaArgs a) {
    ga_body<64, 8, false, true>(blockIdx.x, threadIdx.x, a.f0, a.dec0, a.idx2, nullptr,
                                a.out, nullptr, nullptr);
}

extern "C" void kernel_launch(void* const* d_in, const int* in_sizes, int n_in,
                              void* d_out, int out_size, void* d_ws, size_t ws_size,
                              hipStream_t stream) {
    // ---- workspace layout ----
    char* wsb = (char*)d_ws;
    unsigned short* f3bf = (unsigned short*)wsb;              // 4MB
    unsigned short* dec2 = (unsigned short*)(wsb + 4 * MB);   // 2MB
    unsigned short* dec1 = (unsigned short*)(wsb + 6 * MB);   // 4MB
    unsigned short* dec0 = (unsigned short*)(wsb + 10 * MB);  // 8MB
    unsigned short* f2p  = (unsigned short*)(wsb + 18 * MB);  // 8MB
    unsigned short* f1p  = (unsigned short*)(wsb + 26 * MB);  // 16MB
    int* cnt2 = (int*)(wsb + 42 * MB);                        // contiguous zero region
    int* cnt1 = cnt2 + PN2;
    float* part2 = (float*)(cnt1 + PN1);                      // 128*512*2
    float* part1 = part2 + 128 * 512 * 2;                     // 256*256*2
    float* part0 = part1 + 256 * 256 * 2;                     // 512*128*2

    MegaArgs a;
    a.f0 = (const float*)d_in[0];
    a.f1 = (const float*)d_in[1];
    a.f2 = (const float*)d_in[2];
    a.f3 = (const float*)d_in[3];
    a.bnw2 = (const float*)d_in[4];
    a.bnb2 = (const float*)d_in[5];
    a.W2 = (const float*)d_in[6];
    a.bnw1 = (const float*)d_in[7];
    a.bnb1 = (const float*)d_in[8];
    a.W1 = (const float*)d_in[9];
    a.bnw0 = (const float*)d_in[10];
    a.bnb0 = (const float*)d_in[11];
    a.W0 = (const float*)d_in[12];
    a.idx0 = (const int*)d_in[13];
    a.idx1 = (const int*)d_in[14];
    a.idx2 = (const int*)d_in[15];
    a.f3bf = f3bf; a.dec2 = dec2; a.dec1 = dec1; a.dec0 = dec0;
    a.f2p = f2p; a.f1p = f1p;
    a.cnt2 = cnt2; a.cnt1 = cnt1;
    a.part2 = part2; a.part1 = part1; a.part0 = part0;
    a.out = (float*)d_out;

    hipMemsetAsync(cnt2, 0, (size_t)(PN2 + PN1) * sizeof(int), stream);

    k_p1<<<416, 256, 0, stream>>>(a);   // 128 stats + 128 cvt + 32+128 hist blocks
    k_g2<<<256, 512, 0, stream>>>(a);   // 32x8 tiles
    k_a2<<<256, 256, 0, stream>>>(a);   // PN2/64 rows-per-block... 256 vbs x 64 rows
    k_g1<<<256, 512, 0, stream>>>(a);   // 128x2 tiles
    k_a1<<<512, 256, 0, stream>>>(a);   // 512 vbs x 128 rows
    k_g0<<<512, 512, 0, stream>>>(a);   // 512 tiles of 128 rows
    k_a0<<<1024, 256, 0, stream>>>(a);  // 1024 vbs x 256 rows
}

// Round 21
// 137.272 us; speedup vs baseline: 1.7341x; 1.1938x over previous
//
#include <hip/hip_runtime.h>

#define BN_EPS 1e-5f

constexpr int PN0 = 262144, PN1 = 65536, PN2 = 16384, PN3 = 4096;
constexpr size_t MB = 1u << 20;

typedef __attribute__((ext_vector_type(8))) short short8;
typedef __attribute__((ext_vector_type(4))) float f32x4;
typedef __attribute__((ext_vector_type(4))) unsigned int u32x4;

__device__ __forceinline__ unsigned f2bf(float f) {
    unsigned u = __builtin_bit_cast(unsigned, f);
    u += 0x7fff + ((u >> 16) & 1);
    return u >> 16;
}
__device__ __forceinline__ float bf2f(unsigned h) {
    return __builtin_bit_cast(float, h << 16);
}
__device__ __forceinline__ f32x4 ntload4(const float* p) {
    return __builtin_nontemporal_load(reinterpret_cast<const f32x4*>(p));
}
__device__ __forceinline__ void ntstore4(float* p, f32x4 v) {
    __builtin_nontemporal_store(v, reinterpret_cast<f32x4*>(p));
}
#define SCHED_FENCE() __builtin_amdgcn_sched_barrier(0)

struct MegaArgs {
    const float *f0, *f1, *f2, *f3;
    const float *bnw2, *bnb2, *W2;
    const float *bnw1, *bnb1, *W1;
    const float *bnw0, *bnb0, *W0;
    const int *idx0, *idx1, *idx2;
    unsigned short *f3bf, *dec2, *dec1, *dec0, *f2p, *f1p;
    int *cnt2, *cnt1;
    float *part2, *part1, *part0;
    float *out;
};

// ---- 256-thread tree reduce of s/q[8] into part[vb] ----
template<int G, int NL>
__device__ __forceinline__ void red_write(float* aux, const float s[8], const float q[8],
                                          int t, int lr, int cgi,
                                          float* part, int vb, int C) {
    #pragma unroll
    for (int j = 0; j < 8; ++j) aux[(lr * G + cgi) * 8 + j] = s[j];
    __syncthreads();
    if (t < G) {
        float ss[8] = {};
        for (int l = 0; l < NL; ++l)
            #pragma unroll
            for (int j = 0; j < 8; ++j) ss[j] += aux[(l * G + t) * 8 + j];
        #pragma unroll
        for (int j = 0; j < 8; ++j)
            part[((size_t)vb * C + t * 8 + j) * 2] = ss[j];
    }
    __syncthreads();
    #pragma unroll
    for (int j = 0; j < 8; ++j) aux[(lr * G + cgi) * 8 + j] = q[j];
    __syncthreads();
    if (t < G) {
        float qq[8] = {};
        for (int l = 0; l < NL; ++l)
            #pragma unroll
            for (int j = 0; j < 8; ++j) qq[j] += aux[(l * G + t) * 8 + j];
        #pragma unroll
        for (int j = 0; j < 8; ++j)
            part[((size_t)vb * C + t * 8 + j) * 2 + 1] = qq[j];
    }
}

// ---- P1: stats over gathered f3[idx0] (vb<128) || f3->bf16 (vb<256) || hists ----
__global__ __launch_bounds__(256) void k_p1(MegaArgs a) {
    __shared__ float aux[2048];
    const int vb = blockIdx.x;
    const int t = threadIdx.x;
    if (vb < 128) {
        const int cgi = t & 63, lr = t >> 6;
        const int r0 = vb * 128;
        float s[8] = {}, q[8] = {};
        for (int ii = 0; ii < 4; ++ii) {
            int gi[8];
            #pragma unroll
            for (int j = 0; j < 8; ++j) gi[j] = a.idx0[r0 + lr + 4 * (ii * 8 + j)];
            float4 x0[8], x1[8];
            #pragma unroll
            for (int j = 0; j < 8; ++j) {
                const float* p = a.f3 + (size_t)gi[j] * 512 + cgi * 8;
                x0[j] = *reinterpret_cast<const float4*>(p);
                x1[j] = *reinterpret_cast<const float4*>(p + 4);
            }
            SCHED_FENCE();
            #pragma unroll
            for (int j = 0; j < 8; ++j) {
                float v[8] = {x0[j].x, x0[j].y, x0[j].z, x0[j].w,
                              x1[j].x, x1[j].y, x1[j].z, x1[j].w};
                #pragma unroll
                for (int k = 0; k < 8; ++k) { s[k] += v[k]; q[k] += v[k] * v[k]; }
            }
        }
        red_write<64, 4>(aux, s, q, t, lr, cgi, a.part2, vb, 512);
    } else if (vb < 256) {
        const int cgi = t & 63, lr = t >> 6;
        const int r0 = (vb - 128) * 32;
        float4 x0[8], x1[8];
        #pragma unroll
        for (int i = 0; i < 8; ++i) {
            const float* p = a.f3 + (size_t)(r0 + lr + 4 * i) * 512 + cgi * 8;
            x0[i] = *reinterpret_cast<const float4*>(p);
            x1[i] = *reinterpret_cast<const float4*>(p + 4);
        }
        SCHED_FENCE();
        #pragma unroll
        for (int i = 0; i < 8; ++i) {
            uint4 o;
            o.x = f2bf(x0[i].x) | (f2bf(x0[i].y) << 16);
            o.y = f2bf(x0[i].z) | (f2bf(x0[i].w) << 16);
            o.z = f2bf(x1[i].x) | (f2bf(x1[i].y) << 16);
            o.w = f2bf(x1[i].z) | (f2bf(x1[i].w) << 16);
            *reinterpret_cast<uint4*>(a.f3bf + (size_t)(r0 + lr + 4 * i) * 512 + cgi * 8) = o;
        }
    } else if (vb < 288) {
        int b = vb - 256;
        int v[8];
        #pragma unroll
        for (int i = 0; i < 8; ++i) v[i] = a.idx1[b * 2048 + i * 256 + t];
        SCHED_FENCE();
        #pragma unroll
        for (int i = 0; i < 8; ++i) atomicAdd(&a.cnt2[v[i]], 1);
    } else {
        int b = vb - 288;
        int v[8];
        #pragma unroll
        for (int i = 0; i < 8; ++i) v[i] = a.idx2[b * 2048 + i * 256 + t];
        SCHED_FENCE();
        #pragma unroll
        for (int i = 0; i < 8; ++i) atomicAdd(&a.cnt1[v[i]], 1);
    }
}

// ---- per-block scale/shift from partials (into LDS), NT threads ----
template<int K, int NB, int NT>
__device__ void calc_scsh(int tid, const float* part, const float* bnw, const float* bnb,
                          float invN, float* sc, float* sh) {
    for (int c = tid; c < K; c += NT) {
        float s = 0.f, q = 0.f;
        for (int b = 0; b < NB; ++b) {
            float2 p = *reinterpret_cast<const float2*>(part + ((size_t)b * K + c) * 2);
            s += p.x;
            q += p.y;
        }
        float mean = s * invN;
        float var = fmaxf(q * invN - mean * mean, 0.f);
        float scl = bnw[c] * rsqrtf(var + BN_EPS);
        sc[c] = scl;
        sh[c] = bnb[c] - mean * scl;
    }
    __syncthreads();
}

// ---- G2: K=512, 128-row x 32-col tile per block (512 thr), vb=blockIdx ----
__global__ __launch_bounds__(512) void k_g2(MegaArgs a) {
    constexpr int K = 512;
    __shared__ __align__(16) unsigned short Wl[32 * 512];  // 32KB
    __shared__ float scshB[1088];
    float* sc = scshB;
    float* sh = scshB + 512;
    float* dl = scshB + 1024;
    const int tid = threadIdx.x;
    calc_scsh<512, 128, 512>(tid, a.part2, a.bnw2, a.bnb2, 1.f / PN2, sc, sh);
    const int lane = tid & 63;
    const int w = tid >> 6;
    const int l15 = lane & 15, lg = lane >> 4;
    const int n32 = tid >> 4, kc = tid & 15;

    const int vb = blockIdx.x;              // 256 = 32 chunks(128) x 8 panels(32)
    const int chunk = vb & 31, panel = vb >> 5;
    const int row = chunk * 128 + w * 16 + l15;
    const unsigned short* xp = a.f3bf + (size_t)row * K + lg * 8;
    short8 xf[16];
    #pragma unroll
    for (int kk = 0; kk < 16; ++kk)
        xf[kk] = *reinterpret_cast<const short8*>(xp + kk * 32);

    {
        const float* wrow = a.W2 + (size_t)(panel * 32 + n32) * K;
        float dp = 0.f;
        #pragma unroll
        for (int i = 0; i < 4; ++i) {
            int k = kc * 32 + i * 8;
            float4 w0 = *reinterpret_cast<const float4*>(wrow + k);
            float4 w1 = *reinterpret_cast<const float4*>(wrow + k + 4);
            float4 s0 = *reinterpret_cast<const float4*>(&sc[k]);
            float4 s1 = *reinterpret_cast<const float4*>(&sc[k + 4]);
            float4 h0 = *reinterpret_cast<const float4*>(&sh[k]);
            float4 h1 = *reinterpret_cast<const float4*>(&sh[k + 4]);
            dp += h0.x * w0.x + h0.y * w0.y + h0.z * w0.z + h0.w * w0.w
                + h1.x * w1.x + h1.y * w1.y + h1.z * w1.z + h1.w * w1.w;
            uint4 o;
            o.x = f2bf(w0.x * s0.x) | (f2bf(w0.y * s0.y) << 16);
            o.y = f2bf(w0.z * s0.z) | (f2bf(w0.w * s0.w) << 16);
            o.z = f2bf(w1.x * s1.x) | (f2bf(w1.y * s1.y) << 16);
            o.w = f2bf(w1.z * s1.z) | (f2bf(w1.w * s1.w) << 16);
            int si = (n32 * K + k) ^ ((n32 & 7) << 3);
            *reinterpret_cast<uint4*>(&Wl[si]) = o;
        }
        dp += __shfl_xor(dp, 1); dp += __shfl_xor(dp, 2);
        dp += __shfl_xor(dp, 4); dp += __shfl_xor(dp, 8);
        if (kc == 0) dl[n32] = dp;
    }
    __syncthreads();

    f32x4 acc[2];
    acc[0] = (f32x4){0.f, 0.f, 0.f, 0.f};
    acc[1] = (f32x4){0.f, 0.f, 0.f, 0.f};
    #pragma unroll
    for (int kk = 0; kk < 16; ++kk) {
        #pragma unroll
        for (int ni = 0; ni < 2; ++ni) {
            const int si = ((ni * 16 + l15) * K + kk * 32 + lg * 8) ^ ((l15 & 7) << 3);
            short8 wf = *reinterpret_cast<const short8*>(&Wl[si]);
            acc[ni] = __builtin_amdgcn_mfma_f32_16x16x32_bf16(wf, xf[kk], acc[ni], 0, 0, 0);
        }
    }

    const size_t rowoff = (size_t)row * 256 + panel * 32;
    #pragma unroll
    for (int ni = 0; ni < 2; ++ni) {
        float4 dr = *reinterpret_cast<const float4*>(&dl[ni * 16 + lg * 4]);
        size_t off = rowoff + ni * 16 + lg * 4;
        float v0 = dr.x + acc[ni][0];
        float v1 = dr.y + acc[ni][1];
        float v2 = dr.z + acc[ni][2];
        float v3 = dr.w + acc[ni][3];
        *reinterpret_cast<uint2*>(&a.dec2[off]) =
            make_uint2(f2bf(v0) | (f2bf(v1) << 16), f2bf(v2) | (f2bf(v3) << 16));
    }
}

// ---- G1: K=256, 128-row x 64-col tile per block (512 thr), vb=blockIdx ----
__global__ __launch_bounds__(512) void k_g1(MegaArgs a) {
    constexpr int K = 256;
    __shared__ __align__(16) unsigned short Wl[64 * 256];  // 32KB
    __shared__ float scshB[576];
    float* sc = scshB;
    float* sh = scshB + 256;
    float* dl = scshB + 512;
    const int tid = threadIdx.x;
    calc_scsh<256, 256, 512>(tid, a.part1, a.bnw1, a.bnb1, 1.f / PN1, sc, sh);
    const int lane = tid & 63;
    const int w = tid >> 6;
    const int l15 = lane & 15, lg = lane >> 4;
    const int n = tid >> 3, kc = tid & 7;

    const int vb = blockIdx.x;              // 256 = 128 chunks(128) x 2 panels(64)
    const int chunk = vb & 127, panel = vb >> 7;
    const int row = chunk * 128 + w * 16 + l15;
    const unsigned short* xp = a.f2p + (size_t)row * K + lg * 8;
    short8 xf[8];
    #pragma unroll
    for (int kk = 0; kk < 8; ++kk)
        xf[kk] = *reinterpret_cast<const short8*>(xp + kk * 32);

    {
        const float* wrow = a.W1 + (size_t)(panel * 64 + n) * K;
        float dp = 0.f;
        #pragma unroll
        for (int i = 0; i < 4; ++i) {
            int k = kc * 32 + i * 8;
            float4 w0 = *reinterpret_cast<const float4*>(wrow + k);
            float4 w1 = *reinterpret_cast<const float4*>(wrow + k + 4);
            float4 s0 = *reinterpret_cast<const float4*>(&sc[k]);
            float4 s1 = *reinterpret_cast<const float4*>(&sc[k + 4]);
            float4 h0 = *reinterpret_cast<const float4*>(&sh[k]);
            float4 h1 = *reinterpret_cast<const float4*>(&sh[k + 4]);
            dp += h0.x * w0.x + h0.y * w0.y + h0.z * w0.z + h0.w * w0.w
                + h1.x * w1.x + h1.y * w1.y + h1.z * w1.z + h1.w * w1.w;
            uint4 o;
            o.x = f2bf(w0.x * s0.x) | (f2bf(w0.y * s0.y) << 16);
            o.y = f2bf(w0.z * s0.z) | (f2bf(w0.w * s0.w) << 16);
            o.z = f2bf(w1.x * s1.x) | (f2bf(w1.y * s1.y) << 16);
            o.w = f2bf(w1.z * s1.z) | (f2bf(w1.w * s1.w) << 16);
            int si = (n * K + k) ^ ((n & 7) << 3);
            *reinterpret_cast<uint4*>(&Wl[si]) = o;
        }
        dp += __shfl_xor(dp, 1); dp += __shfl_xor(dp, 2); dp += __shfl_xor(dp, 4);
        if (kc == 0) dl[n] = dp;
    }
    __syncthreads();

    f32x4 acc[4];
    #pragma unroll
    for (int ni = 0; ni < 4; ++ni) acc[ni] = (f32x4){0.f, 0.f, 0.f, 0.f};
    #pragma unroll
    for (int kk = 0; kk < 8; ++kk) {
        #pragma unroll
        for (int ni = 0; ni < 4; ++ni) {
            const int si = ((ni * 16 + l15) * K + kk * 32 + lg * 8) ^ ((l15 & 7) << 3);
            short8 wf = *reinterpret_cast<const short8*>(&Wl[si]);
            acc[ni] = __builtin_amdgcn_mfma_f32_16x16x32_bf16(wf, xf[kk], acc[ni], 0, 0, 0);
        }
    }

    const size_t rowoff = (size_t)row * 128 + panel * 64;
    #pragma unroll
    for (int ni = 0; ni < 4; ++ni) {
        float4 dr = *reinterpret_cast<const float4*>(&dl[ni * 16 + lg * 4]);
        size_t off = rowoff + ni * 16 + lg * 4;
        float v0 = dr.x + acc[ni][0];
        float v1 = dr.y + acc[ni][1];
        float v2 = dr.z + acc[ni][2];
        float v3 = dr.w + acc[ni][3];
        *reinterpret_cast<uint2*>(&a.dec1[off]) =
            make_uint2(f2bf(v0) | (f2bf(v1) << 16), f2bf(v2) | (f2bf(v3) << 16));
    }
}

// ---- G0: K=128, 64-col panel staged per block; 128-row tile, vb=blockIdx ----
__global__ __launch_bounds__(512) void k_g0(MegaArgs a) {
    constexpr int K = 128;
    __shared__ __align__(16) unsigned short Wl[64 * 128];  // 16KB
    __shared__ float scshB[320];
    float* sc = scshB;
    float* sh = scshB + 128;
    float* dl = scshB + 256;
    const int tid = threadIdx.x;
    calc_scsh<128, 512, 512>(tid, a.part0, a.bnw0, a.bnb0, 1.f / PN0, sc, sh);
    const int lane = tid & 63;
    const int w = tid >> 6;
    const int l15 = lane & 15, lg = lane >> 4;
    const int n = tid >> 3, kc = tid & 7;

    {
        const float* wrow = a.W0 + (size_t)n * K;
        float dp = 0.f;
        #pragma unroll
        for (int i = 0; i < 2; ++i) {
            int k = kc * 16 + i * 8;
            float4 w0 = *reinterpret_cast<const float4*>(wrow + k);
            float4 w1 = *reinterpret_cast<const float4*>(wrow + k + 4);
            float4 s0 = *reinterpret_cast<const float4*>(&sc[k]);
            float4 s1 = *reinterpret_cast<const float4*>(&sc[k + 4]);
            float4 h0 = *reinterpret_cast<const float4*>(&sh[k]);
            float4 h1 = *reinterpret_cast<const float4*>(&sh[k + 4]);
            dp += h0.x * w0.x + h0.y * w0.y + h0.z * w0.z + h0.w * w0.w
                + h1.x * w1.x + h1.y * w1.y + h1.z * w1.z + h1.w * w1.w;
            uint4 o;
            o.x = f2bf(w0.x * s0.x) | (f2bf(w0.y * s0.y) << 16);
            o.y = f2bf(w0.z * s0.z) | (f2bf(w0.w * s0.w) << 16);
            o.z = f2bf(w1.x * s1.x) | (f2bf(w1.y * s1.y) << 16);
            o.w = f2bf(w1.z * s1.z) | (f2bf(w1.w * s1.w) << 16);
            int si = (n * K + k) ^ ((n & 7) << 3);
            *reinterpret_cast<uint4*>(&Wl[si]) = o;
        }
        dp += __shfl_xor(dp, 1); dp += __shfl_xor(dp, 2); dp += __shfl_xor(dp, 4);
        if (kc == 0) dl[n] = dp;
    }
    __syncthreads();

    float4 dr[4];
    #pragma unroll
    for (int ni = 0; ni < 4; ++ni)
        dr[ni] = *reinterpret_cast<const float4*>(&dl[ni * 16 + lg * 4]);

    const int vb = blockIdx.x;  // 512 tiles of 128 rows (PN1/128)
    const int row = vb * 128 + w * 16 + l15;
    const unsigned short* xp = a.f1p + (size_t)row * K + lg * 8;
    short8 xf[4];
    #pragma unroll
    for (int kk = 0; kk < 4; ++kk)
        xf[kk] = *reinterpret_cast<const short8*>(xp + kk * 32);
    f32x4 acc[4];
    #pragma unroll
    for (int ni = 0; ni < 4; ++ni) acc[ni] = (f32x4){0.f, 0.f, 0.f, 0.f};
    #pragma unroll
    for (int kk = 0; kk < 4; ++kk) {
        #pragma unroll
        for (int ni = 0; ni < 4; ++ni) {
            const int si = ((ni * 16 + l15) * K + kk * 32 + lg * 8) ^ ((l15 & 7) << 3);
            short8 wf = *reinterpret_cast<const short8*>(&Wl[si]);
            acc[ni] = __builtin_amdgcn_mfma_f32_16x16x32_bf16(wf, xf[kk], acc[ni], 0, 0, 0);
        }
    }
    const size_t rowoff = (size_t)row * 64;
    #pragma unroll
    for (int ni = 0; ni < 4; ++ni) {
        size_t off = rowoff + ni * 16 + lg * 4;
        float v0 = dr[ni].x + acc[ni][0];
        float v1 = dr[ni].y + acc[ni][1];
        float v2 = dr[ni].z + acc[ni][2];
        float v3 = dr[ni].w + acc[ni][3];
        *reinterpret_cast<uint2*>(&a.dec0[off]) =
            make_uint2(f2bf(v0) | (f2bf(v1) << 16), f2bf(v2) | (f2bf(v3) << 16));
    }
}

// ---- batched gather-add (256-thread block, vb=blockIdx) ----
template<int C, int IT, bool STATS, bool OUT_F32>
__device__ void ga_body(int vb, int t, const float* base,
                        const unsigned short* dec, const int* idx,
                        const int* cnt_next, void* outv, float* part,
                        float* aux) {
    constexpr int G = C / 8;
    constexpr int NL = 256 / G;
    const int cgi = t % G;
    const int lr = t / G;
    const int r0 = vb * (NL * IT);

    int g[IT];
    #pragma unroll
    for (int i = 0; i < IT; ++i) g[i] = idx[r0 + lr + NL * i];

    float wreg[IT];
    if constexpr (STATS) {
        #pragma unroll
        for (int i = 0; i < IT; ++i) wreg[i] = (float)cnt_next[r0 + lr + NL * i];
    }

    u32x4 dv[IT];
    #pragma unroll
    for (int i = 0; i < IT; ++i)
        dv[i] = *reinterpret_cast<const u32x4*>(dec + (size_t)g[i] * C + cgi * 8);

    f32x4 b0[IT], b1[IT];
    #pragma unroll
    for (int i = 0; i < IT; ++i) {
        const float* bp = base + (size_t)(r0 + lr + NL * i) * C + cgi * 8;
        b0[i] = ntload4(bp);
        b1[i] = ntload4(bp + 4);
    }

    SCHED_FENCE();

    float s[8] = {}, q[8] = {};
    #pragma unroll
    for (int i = 0; i < IT; ++i) {
        const int r = r0 + lr + NL * i;
        float v[8];
        v[0] = b0[i][0] + bf2f(dv[i][0] & 0xffffu);
        v[1] = b0[i][1] + bf2f(dv[i][0] >> 16);
        v[2] = b0[i][2] + bf2f(dv[i][1] & 0xffffu);
        v[3] = b0[i][3] + bf2f(dv[i][1] >> 16);
        v[4] = b1[i][0] + bf2f(dv[i][2] & 0xffffu);
        v[5] = b1[i][1] + bf2f(dv[i][2] >> 16);
        v[6] = b1[i][2] + bf2f(dv[i][3] & 0xffffu);
        v[7] = b1[i][3] + bf2f(dv[i][3] >> 16);
        if constexpr (OUT_F32) {
            float* op = (float*)outv + (size_t)r * C + cgi * 8;
            ntstore4(op, (f32x4){v[0], v[1], v[2], v[3]});
            ntstore4(op + 4, (f32x4){v[4], v[5], v[6], v[7]});
        } else {
            unsigned h[8];
            #pragma unroll
            for (int j = 0; j < 8; ++j) h[j] = f2bf(v[j]);
            u32x4 o = {h[0] | (h[1] << 16), h[2] | (h[3] << 16),
                       h[4] | (h[5] << 16), h[6] | (h[7] << 16)};
            *reinterpret_cast<u32x4*>((unsigned short*)outv + (size_t)r * C + cgi * 8) = o;
            if constexpr (STATS) {
                #pragma unroll
                for (int j = 0; j < 8; ++j) {
                    float rv = bf2f(h[j]);
                    s[j] += wreg[i] * rv;
                    q[j] += wreg[i] * rv * rv;
                }
            }
        }
    }

    if constexpr (STATS)
        red_write<G, NL>(aux, s, q, t, lr, cgi, part, vb, C);
}

__global__ __launch_bounds__(256) void k_a2(MegaArgs a) {
    __shared__ float aux[2048];
    ga_body<256, 8, true, false>(blockIdx.x, threadIdx.x, a.f2, a.dec2, a.idx0, a.cnt2,
                                 a.f2p, a.part1, aux);
}
__global__ __launch_bounds__(256) void k_a1(MegaArgs a) {
    __shared__ float aux[2048];
    ga_body<128, 8, true, false>(blockIdx.x, threadIdx.x, a.f1, a.dec1, a.idx1, a.cnt1,
                                 a.f1p, a.part0, aux);
}
__global__ __launch_bounds__(256) void k_a0(MegaArgs a) {
    ga_body<64, 8, false, true>(blockIdx.x, threadIdx.x, a.f0, a.dec0, a.idx2, nullptr,
                                a.out, nullptr, nullptr);
}

extern "C" void kernel_launch(void* const* d_in, const int* in_sizes, int n_in,
                              void* d_out, int out_size, void* d_ws, size_t ws_size,
                              hipStream_t stream) {
    // ---- workspace layout ----
    char* wsb = (char*)d_ws;
    unsigned short* f3bf = (unsigned short*)wsb;              // 4MB
    unsigned short* dec2 = (unsigned short*)(wsb + 4 * MB);   // 2MB
    unsigned short* dec1 = (unsigned short*)(wsb + 6 * MB);   // 4MB
    unsigned short* dec0 = (unsigned short*)(wsb + 10 * MB);  // 8MB
    unsigned short* f2p  = (unsigned short*)(wsb + 18 * MB);  // 8MB
    unsigned short* f1p  = (unsigned short*)(wsb + 26 * MB);  // 16MB
    int* cnt2 = (int*)(wsb + 42 * MB);                        // contiguous zero region
    int* cnt1 = cnt2 + PN2;
    float* part2 = (float*)(cnt1 + PN1);                      // 128*512*2
    float* part1 = part2 + 128 * 512 * 2;                     // 256*256*2
    float* part0 = part1 + 256 * 256 * 2;                     // 512*128*2

    MegaArgs a;
    a.f0 = (const float*)d_in[0];
    a.f1 = (const float*)d_in[1];
    a.f2 = (const float*)d_in[2];
    a.f3 = (const float*)d_in[3];
    a.bnw2 = (const float*)d_in[4];
    a.bnb2 = (const float*)d_in[5];
    a.W2 = (const float*)d_in[6];
    a.bnw1 = (const float*)d_in[7];
    a.bnb1 = (const float*)d_in[8];
    a.W1 = (const float*)d_in[9];
    a.bnw0 = (const float*)d_in[10];
    a.bnb0 = (const float*)d_in[11];
    a.W0 = (const float*)d_in[12];
    a.idx0 = (const int*)d_in[13];
    a.idx1 = (const int*)d_in[14];
    a.idx2 = (const int*)d_in[15];
    a.f3bf = f3bf; a.dec2 = dec2; a.dec1 = dec1; a.dec0 = dec0;
    a.f2p = f2p; a.f1p = f1p;
    a.cnt2 = cnt2; a.cnt1 = cnt1;
    a.part2 = part2; a.part1 = part1; a.part0 = part0;
    a.out = (float*)d_out;

    hipMemsetAsync(cnt2, 0, (size_t)(PN2 + PN1) * sizeof(int), stream);

    k_p1<<<416, 256, 0, stream>>>(a);
    k_g2<<<256, 512, 0, stream>>>(a);
    k_a2<<<256, 256, 0, stream>>>(a);
    k_g1<<<256, 512, 0, stream>>>(a);
    k_a1<<<512, 256, 0, stream>>>(a);
    k_g0<<<512, 512, 0, stream>>>(a);
    k_a0<<<1024, 256, 0, stream>>>(a);
}

// Round 22
// 135.358 us; speedup vs baseline: 1.7586x; 1.0141x over previous
//
#include <hip/hip_runtime.h>

#define BN_EPS 1e-5f

constexpr int PN0 = 262144, PN1 = 65536, PN2 = 16384, PN3 = 4096;
constexpr size_t MB = 1u << 20;

typedef __attribute__((ext_vector_type(8))) short short8;
typedef __attribute__((ext_vector_type(4))) float f32x4;
typedef __attribute__((ext_vector_type(4))) unsigned int u32x4;

__device__ __forceinline__ unsigned f2bf(float f) {
    unsigned u = __builtin_bit_cast(unsigned, f);
    u += 0x7fff + ((u >> 16) & 1);
    return u >> 16;
}
__device__ __forceinline__ float bf2f(unsigned h) {
    return __builtin_bit_cast(float, h << 16);
}
__device__ __forceinline__ f32x4 ntload4(const float* p) {
    return __builtin_nontemporal_load(reinterpret_cast<const f32x4*>(p));
}
__device__ __forceinline__ void ntstore4(float* p, f32x4 v) {
    __builtin_nontemporal_store(v, reinterpret_cast<f32x4*>(p));
}
#define SCHED_FENCE() __builtin_amdgcn_sched_barrier(0)

struct MegaArgs {
    const float *f0, *f1, *f2, *f3;
    const float *bnw2, *bnb2, *W2;
    const float *bnw1, *bnb1, *W1;
    const float *bnw0, *bnb0, *W0;
    const int *idx0, *idx1, *idx2;
    unsigned short *f3bf, *dec2, *dec1, *dec0, *f2p, *f1p;
    int *cnt3, *cnt2, *cnt1;
    float *part2, *part1, *part0;
    float *out;
};

// ---- 256-thread tree reduce of s/q[8] into part[vb] ----
template<int G, int NL>
__device__ __forceinline__ void red_write(float* aux, const float s[8], const float q[8],
                                          int t, int lr, int cgi,
                                          float* part, int vb, int C) {
    #pragma unroll
    for (int j = 0; j < 8; ++j) aux[(lr * G + cgi) * 8 + j] = s[j];
    __syncthreads();
    if (t < G) {
        float ss[8] = {};
        for (int l = 0; l < NL; ++l)
            #pragma unroll
            for (int j = 0; j < 8; ++j) ss[j] += aux[(l * G + t) * 8 + j];
        #pragma unroll
        for (int j = 0; j < 8; ++j)
            part[((size_t)vb * C + t * 8 + j) * 2] = ss[j];
    }
    __syncthreads();
    #pragma unroll
    for (int j = 0; j < 8; ++j) aux[(lr * G + cgi) * 8 + j] = q[j];
    __syncthreads();
    if (t < G) {
        float qq[8] = {};
        for (int l = 0; l < NL; ++l)
            #pragma unroll
            for (int j = 0; j < 8; ++j) qq[j] += aux[(l * G + t) * 8 + j];
        #pragma unroll
        for (int j = 0; j < 8; ++j)
            part[((size_t)vb * C + t * 8 + j) * 2 + 1] = qq[j];
    }
}

// ---- H: histogram idx0 -> cnt3 (must precede weighted stats) ----
__global__ __launch_bounds__(256) void k_h(MegaArgs a) {
    int b = blockIdx.x, t = threadIdx.x;
    int v[8];
    #pragma unroll
    for (int i = 0; i < 8; ++i) v[i] = a.idx0[b * 2048 + i * 256 + t];
    SCHED_FENCE();
    #pragma unroll
    for (int i = 0; i < 8; ++i) atomicAdd(&a.cnt3[v[i]], 1);
}

// ---- P1: cnt3-weighted stats over f3 + f3->bf16 (vb<32, single f3 pass)
//         || hist idx1 (vb<64) || hist idx2 (vb<192) ----
__global__ __launch_bounds__(256) void k_p1(MegaArgs a) {
    __shared__ float aux[2048];
    const int vb = blockIdx.x;
    const int t = threadIdx.x;
    if (vb < 32) {
        const int cgi = t & 63, lr = t >> 6;
        const int r0 = vb * 128;
        float s[8] = {}, q[8] = {};
        for (int ii = 0; ii < 4; ++ii) {
            float w[8];
            float4 x0[8], x1[8];
            int rr[8];
            #pragma unroll
            for (int j = 0; j < 8; ++j) {
                rr[j] = r0 + lr + 4 * (ii * 8 + j);
                w[j] = (float)a.cnt3[rr[j]];
                const float* p = a.f3 + (size_t)rr[j] * 512 + cgi * 8;
                x0[j] = *reinterpret_cast<const float4*>(p);
                x1[j] = *reinterpret_cast<const float4*>(p + 4);
            }
            SCHED_FENCE();
            #pragma unroll
            for (int j = 0; j < 8; ++j) {
                float v[8] = {x0[j].x, x0[j].y, x0[j].z, x0[j].w,
                              x1[j].x, x1[j].y, x1[j].z, x1[j].w};
                uint4 o;
                o.x = f2bf(v[0]) | (f2bf(v[1]) << 16);
                o.y = f2bf(v[2]) | (f2bf(v[3]) << 16);
                o.z = f2bf(v[4]) | (f2bf(v[5]) << 16);
                o.w = f2bf(v[6]) | (f2bf(v[7]) << 16);
                *reinterpret_cast<uint4*>(a.f3bf + (size_t)rr[j] * 512 + cgi * 8) = o;
                #pragma unroll
                for (int k = 0; k < 8; ++k) {
                    s[k] += w[j] * v[k];
                    q[k] += w[j] * v[k] * v[k];
                }
            }
        }
        red_write<64, 4>(aux, s, q, t, lr, cgi, a.part2, vb, 512);
    } else if (vb < 64) {
        int b = vb - 32;
        int v[8];
        #pragma unroll
        for (int i = 0; i < 8; ++i) v[i] = a.idx1[b * 2048 + i * 256 + t];
        SCHED_FENCE();
        #pragma unroll
        for (int i = 0; i < 8; ++i) atomicAdd(&a.cnt2[v[i]], 1);
    } else {
        int b = vb - 64;
        int v[8];
        #pragma unroll
        for (int i = 0; i < 8; ++i) v[i] = a.idx2[b * 2048 + i * 256 + t];
        SCHED_FENCE();
        #pragma unroll
        for (int i = 0; i < 8; ++i) atomicAdd(&a.cnt1[v[i]], 1);
    }
}

// ---- per-block scale/shift from partials (into LDS), NT threads ----
template<int K, int NB, int NT>
__device__ void calc_scsh(int tid, const float* part, const float* bnw, const float* bnb,
                          float invN, float* sc, float* sh) {
    for (int c = tid; c < K; c += NT) {
        float s = 0.f, q = 0.f;
        for (int b = 0; b < NB; ++b) {
            float2 p = *reinterpret_cast<const float2*>(part + ((size_t)b * K + c) * 2);
            s += p.x;
            q += p.y;
        }
        float mean = s * invN;
        float var = fmaxf(q * invN - mean * mean, 0.f);
        float scl = bnw[c] * rsqrtf(var + BN_EPS);
        sc[c] = scl;
        sh[c] = bnb[c] - mean * scl;
    }
    __syncthreads();
}

// ---- G2: K=512, 128-row x 32-col tile per block (512 thr), vb=blockIdx ----
__global__ __launch_bounds__(512) void k_g2(MegaArgs a) {
    constexpr int K = 512;
    __shared__ __align__(16) unsigned short Wl[32 * 512];  // 32KB
    __shared__ float scshB[1088];
    float* sc = scshB;
    float* sh = scshB + 512;
    float* dl = scshB + 1024;
    const int tid = threadIdx.x;
    calc_scsh<512, 32, 512>(tid, a.part2, a.bnw2, a.bnb2, 1.f / PN2, sc, sh);
    const int lane = tid & 63;
    const int w = tid >> 6;
    const int l15 = lane & 15, lg = lane >> 4;
    const int n32 = tid >> 4, kc = tid & 15;

    const int vb = blockIdx.x;              // 256 = 32 chunks(128) x 8 panels(32)
    const int chunk = vb & 31, panel = vb >> 5;
    const int row = chunk * 128 + w * 16 + l15;
    const unsigned short* xp = a.f3bf + (size_t)row * K + lg * 8;
    short8 xf[16];
    #pragma unroll
    for (int kk = 0; kk < 16; ++kk)
        xf[kk] = *reinterpret_cast<const short8*>(xp + kk * 32);

    {
        const float* wrow = a.W2 + (size_t)(panel * 32 + n32) * K;
        float dp = 0.f;
        #pragma unroll
        for (int i = 0; i < 4; ++i) {
            int k = kc * 32 + i * 8;
            float4 w0 = *reinterpret_cast<const float4*>(wrow + k);
            float4 w1 = *reinterpret_cast<const float4*>(wrow + k + 4);
            float4 s0 = *reinterpret_cast<const float4*>(&sc[k]);
            float4 s1 = *reinterpret_cast<const float4*>(&sc[k + 4]);
            float4 h0 = *reinterpret_cast<const float4*>(&sh[k]);
            float4 h1 = *reinterpret_cast<const float4*>(&sh[k + 4]);
            dp += h0.x * w0.x + h0.y * w0.y + h0.z * w0.z + h0.w * w0.w
                + h1.x * w1.x + h1.y * w1.y + h1.z * w1.z + h1.w * w1.w;
            uint4 o;
            o.x = f2bf(w0.x * s0.x) | (f2bf(w0.y * s0.y) << 16);
            o.y = f2bf(w0.z * s0.z) | (f2bf(w0.w * s0.w) << 16);
            o.z = f2bf(w1.x * s1.x) | (f2bf(w1.y * s1.y) << 16);
            o.w = f2bf(w1.z * s1.z) | (f2bf(w1.w * s1.w) << 16);
            int si = (n32 * K + k) ^ ((n32 & 7) << 3);
            *reinterpret_cast<uint4*>(&Wl[si]) = o;
        }
        dp += __shfl_xor(dp, 1); dp += __shfl_xor(dp, 2);
        dp += __shfl_xor(dp, 4); dp += __shfl_xor(dp, 8);
        if (kc == 0) dl[n32] = dp;
    }
    __syncthreads();

    f32x4 acc[2];
    acc[0] = (f32x4){0.f, 0.f, 0.f, 0.f};
    acc[1] = (f32x4){0.f, 0.f, 0.f, 0.f};
    #pragma unroll
    for (int kk = 0; kk < 16; ++kk) {
        #pragma unroll
        for (int ni = 0; ni < 2; ++ni) {
            const int si = ((ni * 16 + l15) * K + kk * 32 + lg * 8) ^ ((l15 & 7) << 3);
            short8 wf = *reinterpret_cast<const short8*>(&Wl[si]);
            acc[ni] = __builtin_amdgcn_mfma_f32_16x16x32_bf16(wf, xf[kk], acc[ni], 0, 0, 0);
        }
    }

    const size_t rowoff = (size_t)row * 256 + panel * 32;
    #pragma unroll
    for (int ni = 0; ni < 2; ++ni) {
        float4 dr = *reinterpret_cast<const float4*>(&dl[ni * 16 + lg * 4]);
        size_t off = rowoff + ni * 16 + lg * 4;
        float v0 = dr.x + acc[ni][0];
        float v1 = dr.y + acc[ni][1];
        float v2 = dr.z + acc[ni][2];
        float v3 = dr.w + acc[ni][3];
        *reinterpret_cast<uint2*>(&a.dec2[off]) =
            make_uint2(f2bf(v0) | (f2bf(v1) << 16), f2bf(v2) | (f2bf(v3) << 16));
    }
}

// ---- G1: K=256, 128-row x 64-col tile per block (512 thr), vb=blockIdx ----
__global__ __launch_bounds__(512) void k_g1(MegaArgs a) {
    constexpr int K = 256;
    __shared__ __align__(16) unsigned short Wl[64 * 256];  // 32KB
    __shared__ float scshB[576];
    float* sc = scshB;
    float* sh = scshB + 256;
    float* dl = scshB + 512;
    const int tid = threadIdx.x;
    calc_scsh<256, 256, 512>(tid, a.part1, a.bnw1, a.bnb1, 1.f / PN1, sc, sh);
    const int lane = tid & 63;
    const int w = tid >> 6;
    const int l15 = lane & 15, lg = lane >> 4;
    const int n = tid >> 3, kc = tid & 7;

    const int vb = blockIdx.x;              // 256 = 128 chunks(128) x 2 panels(64)
    const int chunk = vb & 127, panel = vb >> 7;
    const int row = chunk * 128 + w * 16 + l15;
    const unsigned short* xp = a.f2p + (size_t)row * K + lg * 8;
    short8 xf[8];
    #pragma unroll
    for (int kk = 0; kk < 8; ++kk)
        xf[kk] = *reinterpret_cast<const short8*>(xp + kk * 32);

    {
        const float* wrow = a.W1 + (size_t)(panel * 64 + n) * K;
        float dp = 0.f;
        #pragma unroll
        for (int i = 0; i < 4; ++i) {
            int k = kc * 32 + i * 8;
            float4 w0 = *reinterpret_cast<const float4*>(wrow + k);
            float4 w1 = *reinterpret_cast<const float4*>(wrow + k + 4);
            float4 s0 = *reinterpret_cast<const float4*>(&sc[k]);
            float4 s1 = *reinterpret_cast<const float4*>(&sc[k + 4]);
            float4 h0 = *reinterpret_cast<const float4*>(&sh[k]);
            float4 h1 = *reinterpret_cast<const float4*>(&sh[k + 4]);
            dp += h0.x * w0.x + h0.y * w0.y + h0.z * w0.z + h0.w * w0.w
                + h1.x * w1.x + h1.y * w1.y + h1.z * w1.z + h1.w * w1.w;
            uint4 o;
            o.x = f2bf(w0.x * s0.x) | (f2bf(w0.y * s0.y) << 16);
            o.y = f2bf(w0.z * s0.z) | (f2bf(w0.w * s0.w) << 16);
            o.z = f2bf(w1.x * s1.x) | (f2bf(w1.y * s1.y) << 16);
            o.w = f2bf(w1.z * s1.z) | (f2bf(w1.w * s1.w) << 16);
            int si = (n * K + k) ^ ((n & 7) << 3);
            *reinterpret_cast<uint4*>(&Wl[si]) = o;
        }
        dp += __shfl_xor(dp, 1); dp += __shfl_xor(dp, 2); dp += __shfl_xor(dp, 4);
        if (kc == 0) dl[n] = dp;
    }
    __syncthreads();

    f32x4 acc[4];
    #pragma unroll
    for (int ni = 0; ni < 4; ++ni) acc[ni] = (f32x4){0.f, 0.f, 0.f, 0.f};
    #pragma unroll
    for (int kk = 0; kk < 8; ++kk) {
        #pragma unroll
        for (int ni = 0; ni < 4; ++ni) {
            const int si = ((ni * 16 + l15) * K + kk * 32 + lg * 8) ^ ((l15 & 7) << 3);
            short8 wf = *reinterpret_cast<const short8*>(&Wl[si]);
            acc[ni] = __builtin_amdgcn_mfma_f32_16x16x32_bf16(wf, xf[kk], acc[ni], 0, 0, 0);
        }
    }

    const size_t rowoff = (size_t)row * 128 + panel * 64;
    #pragma unroll
    for (int ni = 0; ni < 4; ++ni) {
        float4 dr = *reinterpret_cast<const float4*>(&dl[ni * 16 + lg * 4]);
        size_t off = rowoff + ni * 16 + lg * 4;
        float v0 = dr.x + acc[ni][0];
        float v1 = dr.y + acc[ni][1];
        float v2 = dr.z + acc[ni][2];
        float v3 = dr.w + acc[ni][3];
        *reinterpret_cast<uint2*>(&a.dec1[off]) =
            make_uint2(f2bf(v0) | (f2bf(v1) << 16), f2bf(v2) | (f2bf(v3) << 16));
    }
}

// ---- G0: K=128, 64-col panel staged per block; 128-row tile, vb=blockIdx ----
__global__ __launch_bounds__(512) void k_g0(MegaArgs a) {
    constexpr int K = 128;
    __shared__ __align__(16) unsigned short Wl[64 * 128];  // 16KB
    __shared__ float scshB[320];
    float* sc = scshB;
    float* sh = scshB + 128;
    float* dl = scshB + 256;
    const int tid = threadIdx.x;
    calc_scsh<128, 512, 512>(tid, a.part0, a.bnw0, a.bnb0, 1.f / PN0, sc, sh);
    const int lane = tid & 63;
    const int w = tid >> 6;
    const int l15 = lane & 15, lg = lane >> 4;
    const int n = tid >> 3, kc = tid & 7;

    {
        const float* wrow = a.W0 + (size_t)n * K;
        float dp = 0.f;
        #pragma unroll
        for (int i = 0; i < 2; ++i) {
            int k = kc * 16 + i * 8;
            float4 w0 = *reinterpret_cast<const float4*>(wrow + k);
            float4 w1 = *reinterpret_cast<const float4*>(wrow + k + 4);
            float4 s0 = *reinterpret_cast<const float4*>(&sc[k]);
            float4 s1 = *reinterpret_cast<const float4*>(&sc[k + 4]);
            float4 h0 = *reinterpret_cast<const float4*>(&sh[k]);
            float4 h1 = *reinterpret_cast<const float4*>(&sh[k + 4]);
            dp += h0.x * w0.x + h0.y * w0.y + h0.z * w0.z + h0.w * w0.w
                + h1.x * w1.x + h1.y * w1.y + h1.z * w1.z + h1.w * w1.w;
            uint4 o;
            o.x = f2bf(w0.x * s0.x) | (f2bf(w0.y * s0.y) << 16);
            o.y = f2bf(w0.z * s0.z) | (f2bf(w0.w * s0.w) << 16);
            o.z = f2bf(w1.x * s1.x) | (f2bf(w1.y * s1.y) << 16);
            o.w = f2bf(w1.z * s1.z) | (f2bf(w1.w * s1.w) << 16);
            int si = (n * K + k) ^ ((n & 7) << 3);
            *reinterpret_cast<uint4*>(&Wl[si]) = o;
        }
        dp += __shfl_xor(dp, 1); dp += __shfl_xor(dp, 2); dp += __shfl_xor(dp, 4);
        if (kc == 0) dl[n] = dp;
    }
    __syncthreads();

    float4 dr[4];
    #pragma unroll
    for (int ni = 0; ni < 4; ++ni)
        dr[ni] = *reinterpret_cast<const float4*>(&dl[ni * 16 + lg * 4]);

    const int vb = blockIdx.x;  // 512 tiles of 128 rows (PN1/128)
    const int row = vb * 128 + w * 16 + l15;
    const unsigned short* xp = a.f1p + (size_t)row * K + lg * 8;
    short8 xf[4];
    #pragma unroll
    for (int kk = 0; kk < 4; ++kk)
        xf[kk] = *reinterpret_cast<const short8*>(xp + kk * 32);
    f32x4 acc[4];
    #pragma unroll
    for (int ni = 0; ni < 4; ++ni) acc[ni] = (f32x4){0.f, 0.f, 0.f, 0.f};
    #pragma unroll
    for (int kk = 0; kk < 4; ++kk) {
        #pragma unroll
        for (int ni = 0; ni < 4; ++ni) {
            const int si = ((ni * 16 + l15) * K + kk * 32 + lg * 8) ^ ((l15 & 7) << 3);
            short8 wf = *reinterpret_cast<const short8*>(&Wl[si]);
            acc[ni] = __builtin_amdgcn_mfma_f32_16x16x32_bf16(wf, xf[kk], acc[ni], 0, 0, 0);
        }
    }
    const size_t rowoff = (size_t)row * 64;
    #pragma unroll
    for (int ni = 0; ni < 4; ++ni) {
        size_t off = rowoff + ni * 16 + lg * 4;
        float v0 = dr[ni].x + acc[ni][0];
        float v1 = dr[ni].y + acc[ni][1];
        float v2 = dr[ni].z + acc[ni][2];
        float v3 = dr[ni].w + acc[ni][3];
        *reinterpret_cast<uint2*>(&a.dec0[off]) =
            make_uint2(f2bf(v0) | (f2bf(v1) << 16), f2bf(v2) | (f2bf(v3) << 16));
    }
}

// ---- batched gather-add (256-thread block, vb=blockIdx) ----
template<int C, int IT, bool STATS, bool OUT_F32>
__device__ void ga_body(int vb, int t, const float* base,
                        const unsigned short* dec, const int* idx,
                        const int* cnt_next, void* outv, float* part,
                        float* aux) {
    constexpr int G = C / 8;
    constexpr int NL = 256 / G;
    const int cgi = t % G;
    const int lr = t / G;
    const int r0 = vb * (NL * IT);

    int g[IT];
    #pragma unroll
    for (int i = 0; i < IT; ++i) g[i] = idx[r0 + lr + NL * i];

    float wreg[IT];
    if constexpr (STATS) {
        #pragma unroll
        for (int i = 0; i < IT; ++i) wreg[i] = (float)cnt_next[r0 + lr + NL * i];
    }

    u32x4 dv[IT];
    #pragma unroll
    for (int i = 0; i < IT; ++i)
        dv[i] = *reinterpret_cast<const u32x4*>(dec + (size_t)g[i] * C + cgi * 8);

    f32x4 b0[IT], b1[IT];
    #pragma unroll
    for (int i = 0; i < IT; ++i) {
        const float* bp = base + (size_t)(r0 + lr + NL * i) * C + cgi * 8;
        b0[i] = ntload4(bp);
        b1[i] = ntload4(bp + 4);
    }

    SCHED_FENCE();

    float s[8] = {}, q[8] = {};
    #pragma unroll
    for (int i = 0; i < IT; ++i) {
        const int r = r0 + lr + NL * i;
        float v[8];
        v[0] = b0[i][0] + bf2f(dv[i][0] & 0xffffu);
        v[1] = b0[i][1] + bf2f(dv[i][0] >> 16);
        v[2] = b0[i][2] + bf2f(dv[i][1] & 0xffffu);
        v[3] = b0[i][3] + bf2f(dv[i][1] >> 16);
        v[4] = b1[i][0] + bf2f(dv[i][2] & 0xffffu);
        v[5] = b1[i][1] + bf2f(dv[i][2] >> 16);
        v[6] = b1[i][2] + bf2f(dv[i][3] & 0xffffu);
        v[7] = b1[i][3] + bf2f(dv[i][3] >> 16);
        if constexpr (OUT_F32) {
            float* op = (float*)outv + (size_t)r * C + cgi * 8;
            ntstore4(op, (f32x4){v[0], v[1], v[2], v[3]});
            ntstore4(op + 4, (f32x4){v[4], v[5], v[6], v[7]});
        } else {
            unsigned h[8];
            #pragma unroll
            for (int j = 0; j < 8; ++j) h[j] = f2bf(v[j]);
            u32x4 o = {h[0] | (h[1] << 16), h[2] | (h[3] << 16),
                       h[4] | (h[5] << 16), h[6] | (h[7] << 16)};
            *reinterpret_cast<u32x4*>((unsigned short*)outv + (size_t)r * C + cgi * 8) = o;
            if constexpr (STATS) {
                #pragma unroll
                for (int j = 0; j < 8; ++j) {
                    float rv = bf2f(h[j]);
                    s[j] += wreg[i] * rv;
                    q[j] += wreg[i] * rv * rv;
                }
            }
        }
    }

    if constexpr (STATS)
        red_write<G, NL>(aux, s, q, t, lr, cgi, part, vb, C);
}

__global__ __launch_bounds__(256) void k_a2(MegaArgs a) {
    __shared__ float aux[2048];
    ga_body<256, 8, true, false>(blockIdx.x, threadIdx.x, a.f2, a.dec2, a.idx0, a.cnt2,
                                 a.f2p, a.part1, aux);
}
__global__ __launch_bounds__(256) void k_a1(MegaArgs a) {
    __shared__ float aux[2048];
    ga_body<128, 8, true, false>(blockIdx.x, threadIdx.x, a.f1, a.dec1, a.idx1, a.cnt1,
                                 a.f1p, a.part0, aux);
}
__global__ __launch_bounds__(256) void k_a0(MegaArgs a) {
    ga_body<64, 8, false, true>(blockIdx.x, threadIdx.x, a.f0, a.dec0, a.idx2, nullptr,
                                a.out, nullptr, nullptr);
}

extern "C" void kernel_launch(void* const* d_in, const int* in_sizes, int n_in,
                              void* d_out, int out_size, void* d_ws, size_t ws_size,
                              hipStream_t stream) {
    // ---- workspace layout ----
    char* wsb = (char*)d_ws;
    unsigned short* f3bf = (unsigned short*)wsb;              // 4MB
    unsigned short* dec2 = (unsigned short*)(wsb + 4 * MB);   // 2MB
    unsigned short* dec1 = (unsigned short*)(wsb + 6 * MB);   // 4MB
    unsigned short* dec0 = (unsigned short*)(wsb + 10 * MB);  // 8MB
    unsigned short* f2p  = (unsigned short*)(wsb + 18 * MB);  // 8MB
    unsigned short* f1p  = (unsigned short*)(wsb + 26 * MB);  // 16MB
    int* cnt3 = (int*)(wsb + 42 * MB);                        // contiguous zero region
    int* cnt2 = cnt3 + PN3;
    int* cnt1 = cnt2 + PN2;
    float* part2 = (float*)(cnt1 + PN1);                      // 32*512*2
    float* part1 = part2 + 32 * 512 * 2;                      // 256*256*2
    float* part0 = part1 + 256 * 256 * 2;                     // 512*128*2

    MegaArgs a;
    a.f0 = (const float*)d_in[0];
    a.f1 = (const float*)d_in[1];
    a.f2 = (const float*)d_in[2];
    a.f3 = (const float*)d_in[3];
    a.bnw2 = (const float*)d_in[4];
    a.bnb2 = (const float*)d_in[5];
    a.W2 = (const float*)d_in[6];
    a.bnw1 = (const float*)d_in[7];
    a.bnb1 = (const float*)d_in[8];
    a.W1 = (const float*)d_in[9];
    a.bnw0 = (const float*)d_in[10];
    a.bnb0 = (const float*)d_in[11];
    a.W0 = (const float*)d_in[12];
    a.idx0 = (const int*)d_in[13];
    a.idx1 = (const int*)d_in[14];
    a.idx2 = (const int*)d_in[15];
    a.f3bf = f3bf; a.dec2 = dec2; a.dec1 = dec1; a.dec0 = dec0;
    a.f2p = f2p; a.f1p = f1p;
    a.cnt3 = cnt3; a.cnt2 = cnt2; a.cnt1 = cnt1;
    a.part2 = part2; a.part1 = part1; a.part0 = part0;
    a.out = (float*)d_out;

    hipMemsetAsync(cnt3, 0, (size_t)(PN3 + PN2 + PN1) * sizeof(int), stream);

    k_h<<<8, 256, 0, stream>>>(a);        // hist idx0 -> cnt3
    k_p1<<<192, 256, 0, stream>>>(a);     // 32 weighted-stats+cvt + 32+128 hist blocks
    k_g2<<<256, 512, 0, stream>>>(a);
    k_a2<<<256, 256, 0, stream>>>(a);
    k_g1<<<256, 512, 0, stream>>>(a);
    k_a1<<<512, 256, 0, stream>>>(a);
    k_g0<<<512, 512, 0, stream>>>(a);
    k_a0<<<1024, 256, 0, stream>>>(a);
}